// Round 8
// baseline (196.888 us; speedup 1.0000x reference)
//
#include <hip/hip_runtime.h>
#include <hip/hip_bf16.h>
#include <math.h>

#define N_PTS 8192
#define C_IN  256
#define OUT_C 256
#define NSAMP 16
#define H_W   32
#define EPSBN 1e-5f
#define GDIM  8
#define NCELL (GDIM * GDIM * GDIM)
#define CAPC  768
#define CAP_H 96
#define GEMM_BLKS 384

typedef short bf16x8 __attribute__((ext_vector_type(8)));
typedef float f32x4  __attribute__((ext_vector_type(4)));

// EXACT arithmetic from the passing rounds: plain expression, default
// compiler contraction, shared by all scans. Do NOT change the rounding.
__device__ __forceinline__ float dist2(const float4 a, const float4 b) {
  float dot = a.x * b.x + a.y * b.y + a.z * b.z;
  return a.w + b.w - 2.0f * dot;
}

__device__ __forceinline__ unsigned long long make_key(float d, int j) {
  unsigned int di = __float_as_uint(d);
  unsigned int ord = ((int)di >= 0) ? (di ^ 0x80000000u) : ~di;
  return ((unsigned long long)ord << 32) | (unsigned int)j;
}

__device__ __forceinline__ void chain_insert(unsigned long long (&ak)[16], unsigned long long key) {
  if (key < ak[0]) {
    #pragma unroll
    for (int s = 0; s < 15; ++s) {
      unsigned long long mn = ak[s] < key ? ak[s] : key;
      unsigned long long nx = ak[s + 1];
      ak[s] = nx > mn ? nx : mn;
    }
    ak[15] = ak[15] < key ? ak[15] : key;
  }
}

// bf16 bit helpers (same rounding as __float2bfloat16 / widening as HW)
__device__ __forceinline__ float b2f(short s) {
  return __uint_as_float(((unsigned int)(unsigned short)s) << 16);
}
__device__ __forceinline__ short f2b(float v) {
  __hip_bfloat16 h = __float2bfloat16(v);
  short s;
  __builtin_memcpy(&s, &h, 2);
  return s;
}

// ---------------------------------------------------------------- prep
__global__ __launch_bounds__(256) void prep_kernel(
    const float* __restrict__ p, const float* __restrict__ x,
    const float* __restrict__ wq, const float* __restrict__ wk, const float* __restrict__ wv,
    const float* __restrict__ bq, const float* __restrict__ bk, const float* __restrict__ bv,
    const float* __restrict__ l1w, const float* __restrict__ l2w,
    const float* __restrict__ bn1g, const float* __restrict__ bn1b,
    const float* __restrict__ bn1m, const float* __restrict__ bn1v,
    float4* __restrict__ p4, __hip_bfloat16* __restrict__ Bp, float* __restrict__ biasp,
    __hip_bfloat16* __restrict__ xb,
    __hip_bfloat16* __restrict__ l1wp, __hip_bfloat16* __restrict__ l2wp,
    float* __restrict__ sc1, float* __restrict__ of1,
    int* __restrict__ cursor, int* __restrict__ pt_cell) {
  int tid = blockIdx.x * blockDim.x + threadIdx.x;
  if (tid < 262144) {  // 8192*256/8 threads, 8 elems each
    const float* xr = &x[(size_t)tid * 8];
    float4 xa = *(const float4*)xr;
    float4 xc = *(const float4*)(xr + 4);
    bf16x8 v;
    v[0] = f2b(xa.x); v[1] = f2b(xa.y); v[2] = f2b(xa.z); v[3] = f2b(xa.w);
    v[4] = f2b(xc.x); v[5] = f2b(xc.y); v[6] = f2b(xc.z); v[7] = f2b(xc.w);
    *(bf16x8*)&xb[(size_t)tid * 8] = v;
  }
  if (tid < 48 * 32 * 16 * 8) {
    int kj = tid & 7, n = (tid >> 3) & 15, kb = (tid >> 7) & 31, nt = tid >> 12;
    int k = kb * 8 + kj, col = nt * 16 + n;
    float v;
    if (col < 256)      v = wq[k * 256 + col];
    else if (col < 512) v = wk[k * 256 + (col - 256)];
    else                v = wv[k * 256 + (col - 512)];
    Bp[tid] = __float2bfloat16(v);
  }
  if (tid < 768) {
    biasp[tid] = tid < 256 ? bq[tid] : (tid < 512 ? bk[tid - 256] : bv[tid - 512]);
  }
  if (tid < 8192) {
    int kj = tid & 7, n = (tid >> 3) & 15, kb = (tid >> 7) & 31, nt = (tid >> 12) & 1;
    int k = kb * 8 + kj, col = nt * 16 + n;
    l1wp[tid] = __float2bfloat16(l1w[k * 32 + col]);
  }
  if (tid < 1024) {
    int kj = tid & 7, n = (tid >> 3) & 15, kb = (tid >> 7) & 3, nt = (tid >> 9) & 1;
    int k = kb * 8 + kj, col = nt * 16 + n;
    l2wp[tid] = __float2bfloat16(l2w[k * 32 + col]);
  }
  if (tid < 256) {
    float s1 = bn1g[tid] * rsqrtf(bn1v[tid] + EPSBN);
    sc1[tid] = s1;
    of1[tid] = bn1b[tid] - bn1m[tid] * s1;
  }
  if (tid < NCELL) cursor[tid] = 0;
  if (tid < N_PTS) {
    float px = p[tid * 3 + 0], py = p[tid * 3 + 1], pz = p[tid * 3 + 2];
    float sq = px * px;
    sq += py * py;
    sq += pz * pz;
    p4[tid] = make_float4(px, py, pz, sq);
    int cx = min(GDIM - 1, max(0, (int)(px * GDIM)));
    int cy = min(GDIM - 1, max(0, (int)(py * GDIM)));
    int cz = min(GDIM - 1, max(0, (int)(pz * GDIM)));
    pt_cell[tid] = (cz * GDIM + cy) * GDIM + cx;
  }
}

// ---------------------------------------------------------------- scatter: in-block LDS histogram + scan + scatter
__global__ __launch_bounds__(512) void scatter_scan(
    const float4* __restrict__ p4, const int* __restrict__ pt_cell,
    int* __restrict__ cell_start, int* __restrict__ cursor,
    float4* __restrict__ sp4, int* __restrict__ sidx, int* __restrict__ rank) {
  __shared__ int buf[NCELL];
  const int t = threadIdx.x;
  buf[t] = 0;
  __syncthreads();
  for (int i = t; i < N_PTS; i += 512) atomicAdd(&buf[pt_cell[i]], 1);
  __syncthreads();
  for (int off = 1; off < NCELL; off <<= 1) {
    int add = (t >= off) ? buf[t - off] : 0;
    __syncthreads();
    buf[t] += add;
    __syncthreads();
  }
  if (blockIdx.x == 0) {
    cell_start[t + 1] = buf[t];
    if (t == 0) cell_start[0] = 0;
  }
  const int pid = blockIdx.x * 512 + t;
  const int c = pt_cell[pid];
  const int start = (c == 0) ? 0 : buf[c - 1];
  const int pos = start + atomicAdd(&cursor[c], 1);
  sp4[pos] = p4[pid];
  sidx[pos] = pid;
  rank[pid] = pos;
}

// ---------------------------------------------------------------- fused de-gathered GEMM + KNN, one dispatch.
// GEMM branch (blocks [0,384)): R7's gemm_qkv verbatim -- original row
// order, consecutive A-rows, no sidx dependency. Scheduled first so its
// MFMA waves fill CU bubbles left by the latency-bound KNN blocks.
// KNN branch: R7's knn_grid verbatim.
__global__ __launch_bounds__(256) void knn_gemm(
    const float4* __restrict__ sp4, const int* __restrict__ sidx,
    const int* __restrict__ cell_start, int* __restrict__ nbr,
    const __hip_bfloat16* __restrict__ xb, const __hip_bfloat16* __restrict__ Bp,
    const float* __restrict__ biasp, __hip_bfloat16* __restrict__ xqkv) {
  if (blockIdx.x < GEMM_BLKS) {
    const int w = threadIdx.x >> 6;
    const int lane = threadIdx.x & 63;
    const int gw = blockIdx.x * 4 + w;
    const int m0 = (gw & 127) * 64;
    const int nt4 = (gw >> 7) * 4;
    const int n = lane & 15, q = lane >> 4;

    f32x4 acc[4][4];
    #pragma unroll
    for (int mi = 0; mi < 4; ++mi)
      #pragma unroll
      for (int ni = 0; ni < 4; ++ni) acc[mi][ni] = (f32x4){0.f, 0.f, 0.f, 0.f};

    for (int k0 = 0; k0 < 256; k0 += 32) {
      bf16x8 af[4], bfr[4];
      #pragma unroll
      for (int mi = 0; mi < 4; ++mi)
        af[mi] = *(const bf16x8*)&xb[(size_t)(m0 + mi * 16 + n) * 256 + k0 + q * 8];
      #pragma unroll
      for (int ni = 0; ni < 4; ++ni)
        bfr[ni] = *(const bf16x8*)&Bp[(size_t)(nt4 + ni) * 4096 + (k0 >> 3) * 128 + q * 128 + n * 8];
      #pragma unroll
      for (int mi = 0; mi < 4; ++mi)
        #pragma unroll
        for (int ni = 0; ni < 4; ++ni)
          acc[mi][ni] = __builtin_amdgcn_mfma_f32_16x16x32_bf16(af[mi], bfr[ni], acc[mi][ni], 0, 0, 0);
    }
    #pragma unroll
    for (int ni = 0; ni < 4; ++ni) {
      int col = (nt4 + ni) * 16 + n;
      float b = biasp[col];
      #pragma unroll
      for (int mi = 0; mi < 4; ++mi)
        #pragma unroll
        for (int r = 0; r < 4; ++r)
          xqkv[(size_t)(m0 + mi * 16 + q * 4 + r) * 768 + col] = __float2bfloat16(acc[mi][ni][r] + b);
    }
    return;
  }

  // ------------------------------ KNN branch (R7 knn_grid verbatim)
  const int kbid = blockIdx.x - GEMM_BLKS;
  const int cell = kbid >> 1;
  const int sub  = kbid & 1;
  const int cs = cell_start[cell], ce = cell_start[cell + 1];
  if (cs + 8 * sub >= ce) return;   // empty sub: skip staging entirely

  __shared__ float4 cpos[CAPC];
  __shared__ int    cidx[CAPC];
  __shared__ unsigned long long hk_s[8][CAP_H];
  __shared__ unsigned long long okey_s[8][16];
  __shared__ float tv_s[8][64];
  __shared__ int cnt_s[8];
  __shared__ int cell_s0_s[27];
  __shared__ int len_s[27];
  __shared__ int pref_s[28];
  __shared__ int nc_s, total_s;

  const int tid = threadIdx.x;
  const int hcx = cell & 7, hcy = (cell >> 3) & 7, hcz = cell >> 6;

  const int ax0 = max(hcx - 1, 0), ax1 = min(hcx + 1, GDIM - 1);
  const int ay0 = max(hcy - 1, 0), ay1 = min(hcy + 1, GDIM - 1);
  const int az0 = max(hcz - 1, 0), az1 = min(hcz + 1, GDIM - 1);
  const int nx = ax1 - ax0 + 1, ny = ay1 - ay0 + 1, nz = az1 - az0 + 1;
  const int nbc = nx * ny * nz;

  if (tid < nbc) {
    int cx = ax0 + tid % nx;
    int cy = ay0 + (tid / nx) % ny;
    int cz = az0 + tid / (nx * ny);
    int cc = (cz * GDIM + cy) * GDIM + cx;
    int s0 = cell_start[cc];
    cell_s0_s[tid] = s0;
    len_s[tid] = cell_start[cc + 1] - s0;
  }
  __syncthreads();
  if (tid == 0) {
    int off = 0;
    for (int m = 0; m < nbc; ++m) { pref_s[m] = off; off += len_s[m]; }
    pref_s[nbc] = off;
    nc_s = nbc;
    total_s = off;
  }
  __syncthreads();
  const int nc = nc_s, total = total_s;

  // staging: one 32-lane group per neighbor cell, coalesced copy
  {
    const int grp = tid >> 5, ln = tid & 31;
    for (int m = grp; m < nbc; m += 8) {
      int base = pref_s[m], src = cell_s0_s[m];
      int lim = min(len_s[m], CAPC - base);
      for (int i = ln; i < lim; i += 32) {
        cpos[base + i] = sp4[src + i];
        cidx[base + i] = sidx[src + i];
      }
    }
  }
  __syncthreads();

  const int ptl = tid >> 5, slice = tid & 31;

  for (int p0 = cs + 8 * sub; p0 < ce; p0 += 16) {
    const int np = min(8, ce - p0);
    const bool pok = ptl < np;
    const int ld = pok ? (p0 + ptl) : cs;
    const float4 pi = sp4[ld];
    const int orig = sidx[ld];

    if (tid < 8) cnt_s[tid] = 0;
    if (tid < 128) okey_s[tid >> 4][tid & 15] = ~0ULL;
    __syncthreads();

    // phase 1: per-slice 2 smallest distances (no chains, no merges)
    float t0 = 3.0e38f, t1 = 3.0e38f;  // t0 <= t1
    for (int idx = slice; idx < total; idx += 32) {
      float4 q;
      if (idx < CAPC) q = cpos[idx];
      else {
        int c = 0;
        while (c + 1 < nc && pref_s[c + 1] <= idx) ++c;
        q = sp4[cell_s0_s[c] + (idx - pref_s[c])];
      }
      float d = dist2(pi, q);
      if (d < t1) {
        if (d < t0) { t1 = t0; t0 = d; } else { t1 = d; }
      }
    }
    tv_s[ptl][slice * 2]     = t0;
    tv_s[ptl][slice * 2 + 1] = t1;
    __syncthreads();

    // 16th-smallest of the 64-value union via strict-rank (broadcast reads)
    int r0 = 0, r1 = 0;
    #pragma unroll 8
    for (int j = 0; j < 64; ++j) {
      float wv = tv_s[ptl][j];
      r0 += (wv < t0) ? 1 : 0;
      r1 += (wv < t1) ? 1 : 0;
    }
    float cand = fmaxf(r0 <= 15 ? t0 : -3.0e38f, r1 <= 15 ? t1 : -3.0e38f);
    cand = fmaxf(cand, __shfl_xor(cand, 1, 64));
    cand = fmaxf(cand, __shfl_xor(cand, 2, 64));
    cand = fmaxf(cand, __shfl_xor(cand, 4, 64));
    cand = fmaxf(cand, __shfl_xor(cand, 8, 64));
    cand = fmaxf(cand, __shfl_xor(cand, 16, 64));
    const float d16 = cand;   // >= true d16; #(d<=d16) >= 16 when total>=16

    // conservative guard box from d16 (contains the true 16-NN ball)
    const float rg = sqrtf(fmaxf(d16, 0.f)) * 1.001f + 1e-4f;
    const int lx = (int)fminf(fmaxf(floorf((pi.x - rg) * GDIM), 0.f), (float)(GDIM - 1));
    const int ux = (int)fminf(fmaxf(floorf((pi.x + rg) * GDIM), 0.f), (float)(GDIM - 1));
    const int ly = (int)fminf(fmaxf(floorf((pi.y - rg) * GDIM), 0.f), (float)(GDIM - 1));
    const int uy = (int)fminf(fmaxf(floorf((pi.y + rg) * GDIM), 0.f), (float)(GDIM - 1));
    const int lz = (int)fminf(fmaxf(floorf((pi.z - rg) * GDIM), 0.f), (float)(GDIM - 1));
    const int uz = (int)fminf(fmaxf(floorf((pi.z + rg) * GDIM), 0.f), (float)(GDIM - 1));
    const bool trigger = (lx < ax0 || ux > ax1 || ly < ay0 || uy > ay1 || lz < az0 || uz > az1);

    // phase 2: threshold collect of (dist, idx) keys
    if (pok) {
      for (int idx = slice; idx < total; idx += 32) {
        float4 q;
        int qi;
        if (idx < CAPC) { q = cpos[idx]; qi = cidx[idx]; }
        else {
          int c = 0;
          while (c + 1 < nc && pref_s[c + 1] <= idx) ++c;
          int g = cell_s0_s[c] + (idx - pref_s[c]);
          q = sp4[g]; qi = sidx[g];
        }
        float d = dist2(pi, q);
        if (d <= d16) {
          int pos = atomicAdd(&cnt_s[ptl], 1);
          if (pos < CAP_H) hk_s[ptl][pos] = make_key(d, qi);
        }
      }
      if (trigger) {
        for (int cz = lz; cz <= uz; ++cz)
          for (int cy = ly; cy <= uy; ++cy)
            for (int cx = lx; cx <= ux; ++cx) {
              if (cx >= ax0 && cx <= ax1 && cy >= ay0 && cy <= ay1 && cz >= az0 && cz <= az1)
                continue;
              int cc = (cz * GDIM + cy) * GDIM + cx;
              int s0 = cell_start[cc], e0 = cell_start[cc + 1];
              for (int k = s0 + slice; k < e0; k += 32) {
                float d = dist2(pi, sp4[k]);
                if (d <= d16) {
                  int pos = atomicAdd(&cnt_s[ptl], 1);
                  if (pos < CAP_H) hk_s[ptl][pos] = make_key(d, sidx[k]);
                }
              }
            }
      }
    }
    __syncthreads();

    const int cntr = cnt_s[ptl];
    const bool overflow = cntr > CAP_H;   // needs 97+ candidates <= d16 (~never)
    const int cnt = overflow ? 0 : cntr;

    // exact rank-select of top-16 among collected keys
    if (pok) {
      for (int i = slice; i < cnt; i += 32) {
        unsigned long long key = hk_s[ptl][i];
        int rk = 0;
        for (int j = 0; j < cnt; ++j) rk += (hk_s[ptl][j] < key) ? 1 : 0;
        if (rk < 16) okey_s[ptl][rk] = key;
      }
    }
    __syncthreads();

    if (!overflow) {
      if (pok && slice < 16) {
        unsigned long long key = okey_s[ptl][15 - slice];
        nbr[orig * NSAMP + slice] = (int)(key & 0xFFFFFFFFu);
      }
    } else if (pok && slice == 0) {
      // exact serial fallback (~never taken)
      unsigned long long akm[16];
      #pragma unroll
      for (int s = 0; s < 16; ++s) akm[s] = ~0ULL;
      for (int idx2 = 0; idx2 < total; ++idx2) {
        float4 q; int qi;
        if (idx2 < CAPC) { q = cpos[idx2]; qi = cidx[idx2]; }
        else {
          int c = 0;
          while (c + 1 < nc && pref_s[c + 1] <= idx2) ++c;
          int g = cell_s0_s[c] + (idx2 - pref_s[c]);
          q = sp4[g]; qi = sidx[g];
        }
        chain_insert(akm, make_key(dist2(pi, q), qi));
      }
      float r;
      if (akm[0] == ~0ULL) r = 1e9f;
      else {
        unsigned int ord = (unsigned int)(akm[0] >> 32);
        unsigned int di = (ord & 0x80000000u) ? (ord ^ 0x80000000u) : ~ord;
        float dd = __uint_as_float(di);
        r = sqrtf(fmaxf(dd, 0.f)) * 1.001f + 1e-4f;
      }
      int flx = (int)fminf(fmaxf(floorf((pi.x - r) * GDIM), 0.f), (float)(GDIM - 1));
      int fux = (int)fminf(fmaxf(floorf((pi.x + r) * GDIM), 0.f), (float)(GDIM - 1));
      int fly = (int)fminf(fmaxf(floorf((pi.y - r) * GDIM), 0.f), (float)(GDIM - 1));
      int fuy = (int)fminf(fmaxf(floorf((pi.y + r) * GDIM), 0.f), (float)(GDIM - 1));
      int flz = (int)fminf(fmaxf(floorf((pi.z - r) * GDIM), 0.f), (float)(GDIM - 1));
      int fuz = (int)fminf(fmaxf(floorf((pi.z + r) * GDIM), 0.f), (float)(GDIM - 1));
      for (int cz = flz; cz <= fuz; ++cz)
        for (int cy = fly; cy <= fuy; ++cy)
          for (int cx = flx; cx <= fux; ++cx) {
            if (cx >= ax0 && cx <= ax1 && cy >= ay0 && cy <= ay1 && cz >= az0 && cz <= az1)
              continue;
            int cc = (cz * GDIM + cy) * GDIM + cx;
            int s0 = cell_start[cc], e0 = cell_start[cc + 1];
            for (int k = s0; k < e0; ++k)
              chain_insert(akm, make_key(dist2(pi, sp4[k]), sidx[k]));
          }
      #pragma unroll
      for (int s = 0; s < 16; ++s) nbr[orig * NSAMP + s] = (int)(akm[s] & 0xFFFFFFFFu);
    }
    __syncthreads();
  }
}

// ---------------------------------------------------------------- fused per-point transform: 2 points/block, all-wave MFMA
// xqkv is ORIGINAL-order: Q row = iorig, K/V rows = nbr ids directly.
__global__ __launch_bounds__(256) void fused_pt(
    const float4* __restrict__ sp4, const int* __restrict__ sidx, const int* __restrict__ rank,
    const __hip_bfloat16* __restrict__ xqkv, const int* __restrict__ nbr,
    const float* __restrict__ pw1, const float* __restrict__ pb1,
    const float* __restrict__ pbng, const float* __restrict__ pbnb,
    const float* __restrict__ pbnm, const float* __restrict__ pbnv,
    const float* __restrict__ pw2, const float* __restrict__ pb2,
    const float* __restrict__ sc1, const float* __restrict__ of1,
    const __hip_bfloat16* __restrict__ l1wp, const float* __restrict__ l1b,
    const float* __restrict__ bn2g, const float* __restrict__ bn2b,
    const float* __restrict__ bn2m, const float* __restrict__ bn2v,
    const __hip_bfloat16* __restrict__ l2wp, const float* __restrict__ l2b,
    float* __restrict__ out) {
  __shared__ __align__(16) __hip_bfloat16 a_s[2][NSAMP][264];
  __shared__ __align__(16) __hip_bfloat16 h1_s[2][NSAMP][40];
  __shared__ float w_s[2][NSAMP][33];
  __shared__ float q3_s[2][NSAMP][4];
  __shared__ int jo[2][NSAMP];
  __shared__ float psum[2][2][264];
  __shared__ int iorig[2];

  const int b0 = blockIdx.x * 2;
  const int tid = threadIdx.x;

  if (tid < 32) {
    int spt = tid >> 4, t = tid & 15;
    int b = b0 + spt;
    int i = sidx[b];
    if (t == 0) iorig[spt] = i;
    int j = nbr[i * NSAMP + t];
    int k = rank[j];
    jo[spt][t] = j;
    float4 pj = sp4[k];
    float4 pc = sp4[b];
    float rx = pj.x - pc.x;
    float ry = pj.y - pc.y;
    float rz = pj.z - pc.z;
    #pragma unroll
    for (int c3 = 0; c3 < 3; ++c3) {
      float t2 = rx * pw1[0 * 3 + c3] + ry * pw1[1 * 3 + c3] + rz * pw1[2 * 3 + c3] + pb1[c3];
      t2 = (t2 - pbnm[c3]) * rsqrtf(pbnv[c3] + EPSBN) * pbng[c3] + pbnb[c3];
      q3_s[spt][t][c3] = fmaxf(t2, 0.f);
    }
  }
  __syncthreads();

  const int pt = tid >> 7;
  const int t127 = tid & 127;
  const int g = t127 >> 5;
  const int cg = (t127 & 31) * 8;
  const int brow = iorig[pt];

  float xqv[8], s1v[8], o1v[8], w20v[8], w21v[8], w22v[8], pb2v[8];
  {
    bf16x8 xq8 = *(const bf16x8*)&xqkv[(size_t)brow * 768 + cg];
    #pragma unroll
    for (int u = 0; u < 8; ++u) {
      int c = cg + u;
      xqv[u] = b2f(xq8[u]);
      s1v[u] = sc1[c];
      o1v[u] = of1[c];
      w20v[u] = pw2[c];
      w21v[u] = pw2[256 + c];
      w22v[u] = pw2[512 + c];
      pb2v[u] = pb2[c];
    }
  }

  #pragma unroll
  for (int pass = 0; pass < 4; ++pass) {
    int t = g + pass * 4;
    int k = jo[pt][t];
    float q30 = q3_s[pt][t][0], q31 = q3_s[pt][t][1], q32 = q3_s[pt][t][2];
    bf16x8 xk8 = *(const bf16x8*)&xqkv[(size_t)k * 768 + 256 + cg];
    bf16x8 av;
    #pragma unroll
    for (int u = 0; u < 8; ++u) {
      float prv = q30 * w20v[u] + q31 * w21v[u] + q32 * w22v[u] + pb2v[u];
      float r = b2f(xk8[u]) - xqv[u] + prv;
      av[u] = f2b(fmaxf(r * s1v[u] + o1v[u], 0.f));
    }
    *(bf16x8*)&a_s[pt][t][cg] = av;
  }
  __syncthreads();

  const int w = tid >> 6;
  const int lane = tid & 63;
  const int mpt = w >> 1, hh = w & 1;
  const int nn = lane & 15, q = lane >> 4;
  {
    f32x4 acc = {0.f, 0.f, 0.f, 0.f};
    #pragma unroll
    for (int k0 = 0; k0 < 256; k0 += 32) {
      bf16x8 a = *(const bf16x8*)&a_s[mpt][nn][k0 + q * 8];
      bf16x8 bb = *(const bf16x8*)&l1wp[hh * 4096 + (k0 >> 3) * 128 + q * 128 + nn * 8];
      acc = __builtin_amdgcn_mfma_f32_16x16x32_bf16(a, bb, acc, 0, 0, 0);
    }
    int h = hh * 16 + nn;
    float s2 = bn2g[h] * rsqrtf(bn2v[h] + EPSBN);
    float o2 = bn2b[h] - bn2m[h] * s2;
    float l1bh = l1b[h];
    #pragma unroll
    for (int r = 0; r < 4; ++r)
      h1_s[mpt][q * 4 + r][h] = __float2bfloat16(fmaxf((acc[r] + l1bh) * s2 + o2, 0.f));
  }
  __syncthreads();

  {
    bf16x8 a = *(const bf16x8*)&h1_s[mpt][nn][q * 8];
    bf16x8 bb = *(const bf16x8*)&l2wp[hh * 512 + q * 128 + nn * 8];
    f32x4 z = {0.f, 0.f, 0.f, 0.f};
    f32x4 d = __builtin_amdgcn_mfma_f32_16x16x32_bf16(a, bb, z, 0, 0, 0);
    int h = hh * 16 + nn;
    float l2bh = l2b[h];
    #pragma unroll
    for (int r = 0; r < 4; ++r) w_s[mpt][q * 4 + r][h] = d[r] + l2bh;
  }
  __syncthreads();

  if (tid < 64) {
    int spt = tid >> 5, h = tid & 31;
    float m = -1e30f;
    #pragma unroll
    for (int t = 0; t < NSAMP; ++t) m = fmaxf(m, w_s[spt][t][h]);
    float e[NSAMP];
    float ssum = 0.f;
    #pragma unroll
    for (int t = 0; t < NSAMP; ++t) { e[t] = __expf(w_s[spt][t][h] - m); ssum += e[t]; }
    float inv = 1.f / ssum;
    #pragma unroll
    for (int t = 0; t < NSAMP; ++t) w_s[spt][t][h] = e[t] * inv;
  }
  __syncthreads();

  const int hb = cg & 31;
  float acc8[8];
  #pragma unroll
  for (int u = 0; u < 8; ++u) acc8[u] = 0.f;
  #pragma unroll
  for (int pass = 0; pass < 4; ++pass) {
    int t = g + pass * 4;
    int k = jo[pt][t];
    float q30 = q3_s[pt][t][0], q31 = q3_s[pt][t][1], q32 = q3_s[pt][t][2];
    bf16x8 xv8 = *(const bf16x8*)&xqkv[(size_t)k * 768 + 512 + cg];
    #pragma unroll
    for (int u = 0; u < 8; ++u) {
      float prv = q30 * w20v[u] + q31 * w21v[u] + q32 * w22v[u] + pb2v[u];
      acc8[u] += (b2f(xv8[u]) + prv) * w_s[pt][t][hb + u];
    }
  }
  #pragma unroll
  for (int u = 0; u < 8; ++u) acc8[u] += __shfl_xor(acc8[u], 32, 64);
  if ((lane >> 5) == 0) {
    #pragma unroll
    for (int u = 0; u < 8; ++u) psum[mpt][hh][cg + u] = acc8[u];
  }
  __syncthreads();
  {
    int opt = tid >> 7;
    int c0 = (tid & 127) * 2;
    float v0 = psum[opt][0][c0] + psum[opt][1][c0];
    float v1 = psum[opt][0][c0 + 1] + psum[opt][1][c0 + 1];
    int io = iorig[opt];
    *(float2*)&out[(size_t)io * OUT_C + c0] = make_float2(v0, v1);
  }
}

// ---------------------------------------------------------------- launch
extern "C" void kernel_launch(void* const* d_in, const int* in_sizes, int n_in,
                              void* d_out, int out_size, void* d_ws, size_t ws_size,
                              hipStream_t stream) {
  const float* p    = (const float*)d_in[0];
  const float* x    = (const float*)d_in[1];
  const float* wq   = (const float*)d_in[2];
  const float* bq   = (const float*)d_in[3];
  const float* wk   = (const float*)d_in[4];
  const float* bk   = (const float*)d_in[5];
  const float* wv   = (const float*)d_in[6];
  const float* bv   = (const float*)d_in[7];
  const float* pw1  = (const float*)d_in[8];
  const float* pb1  = (const float*)d_in[9];
  const float* pbng = (const float*)d_in[10];
  const float* pbnb = (const float*)d_in[11];
  const float* pbnm = (const float*)d_in[12];
  const float* pbnv = (const float*)d_in[13];
  const float* pw2  = (const float*)d_in[14];
  const float* pb2  = (const float*)d_in[15];
  const float* bn1g = (const float*)d_in[16];
  const float* bn1b = (const float*)d_in[17];
  const float* bn1m = (const float*)d_in[18];
  const float* bn1v = (const float*)d_in[19];
  const float* l1w  = (const float*)d_in[20];
  const float* l1b  = (const float*)d_in[21];
  const float* bn2g = (const float*)d_in[22];
  const float* bn2b = (const float*)d_in[23];
  const float* bn2m = (const float*)d_in[24];
  const float* bn2v = (const float*)d_in[25];
  const float* l2w  = (const float*)d_in[26];
  const float* l2b  = (const float*)d_in[27];
  float* out = (float*)d_out;

  char* ws = (char*)d_ws;
  float4* p4       = (float4*)(ws + 0x000000);
  float*  biasp    = (float*)(ws + 0x040000);
  int*    cursor   = (int*)(ws + 0x042800);
  int*    cell_st  = (int*)(ws + 0x043000);
  int*    pt_cell  = (int*)(ws + 0x044000);
  float4* sp4      = (float4*)(ws + 0x050000);
  int*    sidx     = (int*)(ws + 0x070000);
  __hip_bfloat16* l1wp = (__hip_bfloat16*)(ws + 0x080000);
  __hip_bfloat16* l2wp = (__hip_bfloat16*)(ws + 0x084000);
  float*  sc1      = (float*)(ws + 0x085000);
  float*  of1      = (float*)(ws + 0x085800);
  int*    rank     = (int*)(ws + 0x088000);
  int*    nbr      = (int*)(ws + 0x090000);
  __hip_bfloat16* Bp   = (__hip_bfloat16*)(ws + 0x110000);
  __hip_bfloat16* xb   = (__hip_bfloat16*)(ws + 0x170000);  // 4MB, ends at 0x570000
  __hip_bfloat16* xqkv = (__hip_bfloat16*)(ws + 0x570000);

  prep_kernel<<<dim3(1024), dim3(256), 0, stream>>>(
      p, x, wq, wk, wv, bq, bk, bv, l1w, l2w, bn1g, bn1b, bn1m, bn1v,
      p4, Bp, biasp, xb, l1wp, l2wp, sc1, of1, cursor, pt_cell);
  scatter_scan<<<dim3(16), dim3(512), 0, stream>>>(
      p4, pt_cell, cell_st, cursor, sp4, sidx, rank);
  knn_gemm<<<dim3(GEMM_BLKS + NCELL * 2), dim3(256), 0, stream>>>(
      sp4, sidx, cell_st, nbr, xb, Bp, biasp, xqkv);
  fused_pt<<<dim3(N_PTS / 2), dim3(256), 0, stream>>>(
      sp4, sidx, rank, xqkv, nbr, pw1, pb1, pbng, pbnb, pbnm, pbnv, pw2, pb2,
      sc1, of1, l1wp, l1b, bn2g, bn2b, bn2m, bn2v, l2wp, l2b, out);
}

// Round 9
// 185.025 us; speedup vs baseline: 1.0641x; 1.0641x over previous
//
#include <hip/hip_runtime.h>
#include <hip/hip_bf16.h>
#include <math.h>

#define N_PTS 8192
#define C_IN  256
#define OUT_C 256
#define NSAMP 16
#define H_W   32
#define EPSBN 1e-5f
#define GDIM  8
#define NCELL (GDIM * GDIM * GDIM)
#define CAPC  768
#define CAP_H 96
#define GEMM_BLKS2 192   // 192 blocks x 8 waves = same 1536 gw as 384 x 4

typedef short bf16x8 __attribute__((ext_vector_type(8)));
typedef float f32x4  __attribute__((ext_vector_type(4)));

// EXACT arithmetic from the passing rounds: plain expression, default
// compiler contraction, shared by all scans. Do NOT change the rounding.
__device__ __forceinline__ float dist2(const float4 a, const float4 b) {
  float dot = a.x * b.x + a.y * b.y + a.z * b.z;
  return a.w + b.w - 2.0f * dot;
}

__device__ __forceinline__ unsigned long long make_key(float d, int j) {
  unsigned int di = __float_as_uint(d);
  unsigned int ord = ((int)di >= 0) ? (di ^ 0x80000000u) : ~di;
  return ((unsigned long long)ord << 32) | (unsigned int)j;
}

__device__ __forceinline__ void chain_insert(unsigned long long (&ak)[16], unsigned long long key) {
  if (key < ak[0]) {
    #pragma unroll
    for (int s = 0; s < 15; ++s) {
      unsigned long long mn = ak[s] < key ? ak[s] : key;
      unsigned long long nx = ak[s + 1];
      ak[s] = nx > mn ? nx : mn;
    }
    ak[15] = ak[15] < key ? ak[15] : key;
  }
}

// bf16 bit helpers (same rounding as __float2bfloat16 / widening as HW)
__device__ __forceinline__ float b2f(short s) {
  return __uint_as_float(((unsigned int)(unsigned short)s) << 16);
}
__device__ __forceinline__ short f2b(float v) {
  __hip_bfloat16 h = __float2bfloat16(v);
  short s;
  __builtin_memcpy(&s, &h, 2);
  return s;
}

// ---------------------------------------------------------------- prep
__global__ __launch_bounds__(256) void prep_kernel(
    const float* __restrict__ p, const float* __restrict__ x,
    const float* __restrict__ wq, const float* __restrict__ wk, const float* __restrict__ wv,
    const float* __restrict__ bq, const float* __restrict__ bk, const float* __restrict__ bv,
    const float* __restrict__ l1w, const float* __restrict__ l2w,
    const float* __restrict__ bn1g, const float* __restrict__ bn1b,
    const float* __restrict__ bn1m, const float* __restrict__ bn1v,
    float4* __restrict__ p4, __hip_bfloat16* __restrict__ Bp, float* __restrict__ biasp,
    __hip_bfloat16* __restrict__ xb,
    __hip_bfloat16* __restrict__ l1wp, __hip_bfloat16* __restrict__ l2wp,
    float* __restrict__ sc1, float* __restrict__ of1,
    int* __restrict__ cursor, int* __restrict__ pt_cell) {
  int tid = blockIdx.x * blockDim.x + threadIdx.x;
  if (tid < 262144) {  // 8192*256/8 threads, 8 elems each
    const float* xr = &x[(size_t)tid * 8];
    float4 xa = *(const float4*)xr;
    float4 xc = *(const float4*)(xr + 4);
    bf16x8 v;
    v[0] = f2b(xa.x); v[1] = f2b(xa.y); v[2] = f2b(xa.z); v[3] = f2b(xa.w);
    v[4] = f2b(xc.x); v[5] = f2b(xc.y); v[6] = f2b(xc.z); v[7] = f2b(xc.w);
    *(bf16x8*)&xb[(size_t)tid * 8] = v;
  }
  if (tid < 48 * 32 * 16 * 8) {
    int kj = tid & 7, n = (tid >> 3) & 15, kb = (tid >> 7) & 31, nt = tid >> 12;
    int k = kb * 8 + kj, col = nt * 16 + n;
    float v;
    if (col < 256)      v = wq[k * 256 + col];
    else if (col < 512) v = wk[k * 256 + (col - 256)];
    else                v = wv[k * 256 + (col - 512)];
    Bp[tid] = __float2bfloat16(v);
  }
  if (tid < 768) {
    biasp[tid] = tid < 256 ? bq[tid] : (tid < 512 ? bk[tid - 256] : bv[tid - 512]);
  }
  if (tid < 8192) {
    int kj = tid & 7, n = (tid >> 3) & 15, kb = (tid >> 7) & 31, nt = (tid >> 12) & 1;
    int k = kb * 8 + kj, col = nt * 16 + n;
    l1wp[tid] = __float2bfloat16(l1w[k * 32 + col]);
  }
  if (tid < 1024) {
    int kj = tid & 7, n = (tid >> 3) & 15, kb = (tid >> 7) & 3, nt = (tid >> 9) & 1;
    int k = kb * 8 + kj, col = nt * 16 + n;
    l2wp[tid] = __float2bfloat16(l2w[k * 32 + col]);
  }
  if (tid < 256) {
    float s1 = bn1g[tid] * rsqrtf(bn1v[tid] + EPSBN);
    sc1[tid] = s1;
    of1[tid] = bn1b[tid] - bn1m[tid] * s1;
  }
  if (tid < NCELL) cursor[tid] = 0;
  if (tid < N_PTS) {
    float px = p[tid * 3 + 0], py = p[tid * 3 + 1], pz = p[tid * 3 + 2];
    float sq = px * px;
    sq += py * py;
    sq += pz * pz;
    p4[tid] = make_float4(px, py, pz, sq);
    int cx = min(GDIM - 1, max(0, (int)(px * GDIM)));
    int cy = min(GDIM - 1, max(0, (int)(py * GDIM)));
    int cz = min(GDIM - 1, max(0, (int)(pz * GDIM)));
    pt_cell[tid] = (cz * GDIM + cy) * GDIM + cx;
  }
}

// ---------------------------------------------------------------- fused scatter + de-gathered QKV GEMM.
// GEMM blocks [0,192) x 8 waves: R7's gemm_qkv, same gw set (identical
// xqkv bits). Scatter blocks [192,208): R7's scatter_scan rebased. The
// GEMM overlaps only the tiny 16-block scatter (machine otherwise idle) --
// NOT the latency-critical KNN (R8 showed that interference costs ~7us).
__global__ __launch_bounds__(512) void scatter_gemm(
    const float4* __restrict__ p4, const int* __restrict__ pt_cell,
    int* __restrict__ cell_start, int* __restrict__ cursor,
    float4* __restrict__ sp4, int* __restrict__ sidx, int* __restrict__ rank,
    const __hip_bfloat16* __restrict__ xb, const __hip_bfloat16* __restrict__ Bp,
    const float* __restrict__ biasp, __hip_bfloat16* __restrict__ xqkv) {
  if (blockIdx.x < GEMM_BLKS2) {
    const int w = threadIdx.x >> 6;          // 0..7
    const int lane = threadIdx.x & 63;
    const int gw = blockIdx.x * 8 + w;       // 0..1535, same set as 384x4
    const int m0 = (gw & 127) * 64;
    const int nt4 = (gw >> 7) * 4;
    const int n = lane & 15, q = lane >> 4;

    f32x4 acc[4][4];
    #pragma unroll
    for (int mi = 0; mi < 4; ++mi)
      #pragma unroll
      for (int ni = 0; ni < 4; ++ni) acc[mi][ni] = (f32x4){0.f, 0.f, 0.f, 0.f};

    for (int k0 = 0; k0 < 256; k0 += 32) {
      bf16x8 af[4], bfr[4];
      #pragma unroll
      for (int mi = 0; mi < 4; ++mi)
        af[mi] = *(const bf16x8*)&xb[(size_t)(m0 + mi * 16 + n) * 256 + k0 + q * 8];
      #pragma unroll
      for (int ni = 0; ni < 4; ++ni)
        bfr[ni] = *(const bf16x8*)&Bp[(size_t)(nt4 + ni) * 4096 + (k0 >> 3) * 128 + q * 128 + n * 8];
      #pragma unroll
      for (int mi = 0; mi < 4; ++mi)
        #pragma unroll
        for (int ni = 0; ni < 4; ++ni)
          acc[mi][ni] = __builtin_amdgcn_mfma_f32_16x16x32_bf16(af[mi], bfr[ni], acc[mi][ni], 0, 0, 0);
    }
    #pragma unroll
    for (int ni = 0; ni < 4; ++ni) {
      int col = (nt4 + ni) * 16 + n;
      float b = biasp[col];
      #pragma unroll
      for (int mi = 0; mi < 4; ++mi)
        #pragma unroll
        for (int r = 0; r < 4; ++r)
          xqkv[(size_t)(m0 + mi * 16 + q * 4 + r) * 768 + col] = __float2bfloat16(acc[mi][ni][r] + b);
    }
    return;
  }

  // ------------------------------ scatter branch (R7 scatter_scan rebased)
  const int sbid = blockIdx.x - GEMM_BLKS2;
  __shared__ int buf[NCELL];
  const int t = threadIdx.x;
  buf[t] = 0;
  __syncthreads();
  for (int i = t; i < N_PTS; i += 512) atomicAdd(&buf[pt_cell[i]], 1);
  __syncthreads();
  for (int off = 1; off < NCELL; off <<= 1) {
    int add = (t >= off) ? buf[t - off] : 0;
    __syncthreads();
    buf[t] += add;
    __syncthreads();
  }
  if (sbid == 0) {
    cell_start[t + 1] = buf[t];
    if (t == 0) cell_start[0] = 0;
  }
  const int pid = sbid * 512 + t;
  const int c = pt_cell[pid];
  const int start = (c == 0) ? 0 : buf[c - 1];
  const int pos = start + atomicAdd(&cursor[c], 1);
  sp4[pos] = p4[pid];
  sidx[pos] = pid;
  rank[pid] = pos;
}

// ---------------------------------------------------------------- exact grid KNN (R7 verbatim)
__global__ __launch_bounds__(256) void knn_grid(
    const float4* __restrict__ sp4, const int* __restrict__ sidx,
    const int* __restrict__ cell_start, int* __restrict__ nbr) {
  const int kbid = blockIdx.x;
  const int cell = kbid >> 1;
  const int sub  = kbid & 1;
  const int cs = cell_start[cell], ce = cell_start[cell + 1];
  if (cs + 8 * sub >= ce) return;   // empty sub: skip staging entirely

  __shared__ float4 cpos[CAPC];
  __shared__ int    cidx[CAPC];
  __shared__ unsigned long long hk_s[8][CAP_H];
  __shared__ unsigned long long okey_s[8][16];
  __shared__ float tv_s[8][64];
  __shared__ int cnt_s[8];
  __shared__ int cell_s0_s[27];
  __shared__ int len_s[27];
  __shared__ int pref_s[28];
  __shared__ int nc_s, total_s;

  const int tid = threadIdx.x;
  const int hcx = cell & 7, hcy = (cell >> 3) & 7, hcz = cell >> 6;

  const int ax0 = max(hcx - 1, 0), ax1 = min(hcx + 1, GDIM - 1);
  const int ay0 = max(hcy - 1, 0), ay1 = min(hcy + 1, GDIM - 1);
  const int az0 = max(hcz - 1, 0), az1 = min(hcz + 1, GDIM - 1);
  const int nx = ax1 - ax0 + 1, ny = ay1 - ay0 + 1, nz = az1 - az0 + 1;
  const int nbc = nx * ny * nz;

  if (tid < nbc) {
    int cx = ax0 + tid % nx;
    int cy = ay0 + (tid / nx) % ny;
    int cz = az0 + tid / (nx * ny);
    int cc = (cz * GDIM + cy) * GDIM + cx;
    int s0 = cell_start[cc];
    cell_s0_s[tid] = s0;
    len_s[tid] = cell_start[cc + 1] - s0;
  }
  __syncthreads();
  if (tid == 0) {
    int off = 0;
    for (int m = 0; m < nbc; ++m) { pref_s[m] = off; off += len_s[m]; }
    pref_s[nbc] = off;
    nc_s = nbc;
    total_s = off;
  }
  __syncthreads();
  const int nc = nc_s, total = total_s;

  // staging: one 32-lane group per neighbor cell, coalesced copy
  {
    const int grp = tid >> 5, ln = tid & 31;
    for (int m = grp; m < nbc; m += 8) {
      int base = pref_s[m], src = cell_s0_s[m];
      int lim = min(len_s[m], CAPC - base);
      for (int i = ln; i < lim; i += 32) {
        cpos[base + i] = sp4[src + i];
        cidx[base + i] = sidx[src + i];
      }
    }
  }
  __syncthreads();

  const int ptl = tid >> 5, slice = tid & 31;

  for (int p0 = cs + 8 * sub; p0 < ce; p0 += 16) {
    const int np = min(8, ce - p0);
    const bool pok = ptl < np;
    const int ld = pok ? (p0 + ptl) : cs;
    const float4 pi = sp4[ld];
    const int orig = sidx[ld];

    if (tid < 8) cnt_s[tid] = 0;
    if (tid < 128) okey_s[tid >> 4][tid & 15] = ~0ULL;
    __syncthreads();

    // phase 1: per-slice 2 smallest distances (no chains, no merges)
    float t0 = 3.0e38f, t1 = 3.0e38f;  // t0 <= t1
    for (int idx = slice; idx < total; idx += 32) {
      float4 q;
      if (idx < CAPC) q = cpos[idx];
      else {
        int c = 0;
        while (c + 1 < nc && pref_s[c + 1] <= idx) ++c;
        q = sp4[cell_s0_s[c] + (idx - pref_s[c])];
      }
      float d = dist2(pi, q);
      if (d < t1) {
        if (d < t0) { t1 = t0; t0 = d; } else { t1 = d; }
      }
    }
    tv_s[ptl][slice * 2]     = t0;
    tv_s[ptl][slice * 2 + 1] = t1;
    __syncthreads();

    // 16th-smallest of the 64-value union via strict-rank (broadcast reads)
    int r0 = 0, r1 = 0;
    #pragma unroll 8
    for (int j = 0; j < 64; ++j) {
      float wv = tv_s[ptl][j];
      r0 += (wv < t0) ? 1 : 0;
      r1 += (wv < t1) ? 1 : 0;
    }
    float cand = fmaxf(r0 <= 15 ? t0 : -3.0e38f, r1 <= 15 ? t1 : -3.0e38f);
    cand = fmaxf(cand, __shfl_xor(cand, 1, 64));
    cand = fmaxf(cand, __shfl_xor(cand, 2, 64));
    cand = fmaxf(cand, __shfl_xor(cand, 4, 64));
    cand = fmaxf(cand, __shfl_xor(cand, 8, 64));
    cand = fmaxf(cand, __shfl_xor(cand, 16, 64));
    const float d16 = cand;   // >= true d16; #(d<=d16) >= 16 when total>=16

    // conservative guard box from d16 (contains the true 16-NN ball)
    const float rg = sqrtf(fmaxf(d16, 0.f)) * 1.001f + 1e-4f;
    const int lx = (int)fminf(fmaxf(floorf((pi.x - rg) * GDIM), 0.f), (float)(GDIM - 1));
    const int ux = (int)fminf(fmaxf(floorf((pi.x + rg) * GDIM), 0.f), (float)(GDIM - 1));
    const int ly = (int)fminf(fmaxf(floorf((pi.y - rg) * GDIM), 0.f), (float)(GDIM - 1));
    const int uy = (int)fminf(fmaxf(floorf((pi.y + rg) * GDIM), 0.f), (float)(GDIM - 1));
    const int lz = (int)fminf(fmaxf(floorf((pi.z - rg) * GDIM), 0.f), (float)(GDIM - 1));
    const int uz = (int)fminf(fmaxf(floorf((pi.z + rg) * GDIM), 0.f), (float)(GDIM - 1));
    const bool trigger = (lx < ax0 || ux > ax1 || ly < ay0 || uy > ay1 || lz < az0 || uz > az1);

    // phase 2: threshold collect of (dist, idx) keys
    if (pok) {
      for (int idx = slice; idx < total; idx += 32) {
        float4 q;
        int qi;
        if (idx < CAPC) { q = cpos[idx]; qi = cidx[idx]; }
        else {
          int c = 0;
          while (c + 1 < nc && pref_s[c + 1] <= idx) ++c;
          int g = cell_s0_s[c] + (idx - pref_s[c]);
          q = sp4[g]; qi = sidx[g];
        }
        float d = dist2(pi, q);
        if (d <= d16) {
          int pos = atomicAdd(&cnt_s[ptl], 1);
          if (pos < CAP_H) hk_s[ptl][pos] = make_key(d, qi);
        }
      }
      if (trigger) {
        for (int cz = lz; cz <= uz; ++cz)
          for (int cy = ly; cy <= uy; ++cy)
            for (int cx = lx; cx <= ux; ++cx) {
              if (cx >= ax0 && cx <= ax1 && cy >= ay0 && cy <= ay1 && cz >= az0 && cz <= az1)
                continue;
              int cc = (cz * GDIM + cy) * GDIM + cx;
              int s0 = cell_start[cc], e0 = cell_start[cc + 1];
              for (int k = s0 + slice; k < e0; k += 32) {
                float d = dist2(pi, sp4[k]);
                if (d <= d16) {
                  int pos = atomicAdd(&cnt_s[ptl], 1);
                  if (pos < CAP_H) hk_s[ptl][pos] = make_key(d, sidx[k]);
                }
              }
            }
      }
    }
    __syncthreads();

    const int cntr = cnt_s[ptl];
    const bool overflow = cntr > CAP_H;   // needs 97+ candidates <= d16 (~never)
    const int cnt = overflow ? 0 : cntr;

    // exact rank-select of top-16 among collected keys
    if (pok) {
      for (int i = slice; i < cnt; i += 32) {
        unsigned long long key = hk_s[ptl][i];
        int rk = 0;
        for (int j = 0; j < cnt; ++j) rk += (hk_s[ptl][j] < key) ? 1 : 0;
        if (rk < 16) okey_s[ptl][rk] = key;
      }
    }
    __syncthreads();

    if (!overflow) {
      if (pok && slice < 16) {
        unsigned long long key = okey_s[ptl][15 - slice];
        nbr[orig * NSAMP + slice] = (int)(key & 0xFFFFFFFFu);
      }
    } else if (pok && slice == 0) {
      // exact serial fallback (~never taken)
      unsigned long long akm[16];
      #pragma unroll
      for (int s = 0; s < 16; ++s) akm[s] = ~0ULL;
      for (int idx2 = 0; idx2 < total; ++idx2) {
        float4 q; int qi;
        if (idx2 < CAPC) { q = cpos[idx2]; qi = cidx[idx2]; }
        else {
          int c = 0;
          while (c + 1 < nc && pref_s[c + 1] <= idx2) ++c;
          int g = cell_s0_s[c] + (idx2 - pref_s[c]);
          q = sp4[g]; qi = sidx[g];
        }
        chain_insert(akm, make_key(dist2(pi, q), qi));
      }
      float r;
      if (akm[0] == ~0ULL) r = 1e9f;
      else {
        unsigned int ord = (unsigned int)(akm[0] >> 32);
        unsigned int di = (ord & 0x80000000u) ? (ord ^ 0x80000000u) : ~ord;
        float dd = __uint_as_float(di);
        r = sqrtf(fmaxf(dd, 0.f)) * 1.001f + 1e-4f;
      }
      int flx = (int)fminf(fmaxf(floorf((pi.x - r) * GDIM), 0.f), (float)(GDIM - 1));
      int fux = (int)fminf(fmaxf(floorf((pi.x + r) * GDIM), 0.f), (float)(GDIM - 1));
      int fly = (int)fminf(fmaxf(floorf((pi.y - r) * GDIM), 0.f), (float)(GDIM - 1));
      int fuy = (int)fminf(fmaxf(floorf((pi.y + r) * GDIM), 0.f), (float)(GDIM - 1));
      int flz = (int)fminf(fmaxf(floorf((pi.z - r) * GDIM), 0.f), (float)(GDIM - 1));
      int fuz = (int)fminf(fmaxf(floorf((pi.z + r) * GDIM), 0.f), (float)(GDIM - 1));
      for (int cz = flz; cz <= fuz; ++cz)
        for (int cy = fly; cy <= fuy; ++cy)
          for (int cx = flx; cx <= fux; ++cx) {
            if (cx >= ax0 && cx <= ax1 && cy >= ay0 && cy <= ay1 && cz >= az0 && cz <= az1)
              continue;
            int cc = (cz * GDIM + cy) * GDIM + cx;
            int s0 = cell_start[cc], e0 = cell_start[cc + 1];
            for (int k = s0; k < e0; ++k)
              chain_insert(akm, make_key(dist2(pi, sp4[k]), sidx[k]));
          }
      #pragma unroll
      for (int s = 0; s < 16; ++s) nbr[orig * NSAMP + s] = (int)(akm[s] & 0xFFFFFFFFu);
    }
    __syncthreads();
  }
}

// ---------------------------------------------------------------- fused per-point transform: 2 points/block, all-wave MFMA
// xqkv is ORIGINAL-order. Positions read from p4 directly (p4[j] ==
// sp4[rank[j]] by construction) -- drops the rank indirection.
__global__ __launch_bounds__(256) void fused_pt(
    const float4* __restrict__ p4, const int* __restrict__ sidx,
    const __hip_bfloat16* __restrict__ xqkv, const int* __restrict__ nbr,
    const float* __restrict__ pw1, const float* __restrict__ pb1,
    const float* __restrict__ pbng, const float* __restrict__ pbnb,
    const float* __restrict__ pbnm, const float* __restrict__ pbnv,
    const float* __restrict__ pw2, const float* __restrict__ pb2,
    const float* __restrict__ sc1, const float* __restrict__ of1,
    const __hip_bfloat16* __restrict__ l1wp, const float* __restrict__ l1b,
    const float* __restrict__ bn2g, const float* __restrict__ bn2b,
    const float* __restrict__ bn2m, const float* __restrict__ bn2v,
    const __hip_bfloat16* __restrict__ l2wp, const float* __restrict__ l2b,
    float* __restrict__ out) {
  __shared__ __align__(16) __hip_bfloat16 a_s[2][NSAMP][264];
  __shared__ __align__(16) __hip_bfloat16 h1_s[2][NSAMP][40];
  __shared__ float w_s[2][NSAMP][33];
  __shared__ float q3_s[2][NSAMP][4];
  __shared__ int jo[2][NSAMP];
  __shared__ float psum[2][2][264];
  __shared__ int iorig[2];

  const int b0 = blockIdx.x * 2;
  const int tid = threadIdx.x;

  if (tid < 32) {
    int spt = tid >> 4, t = tid & 15;
    int b = b0 + spt;
    int i = sidx[b];
    if (t == 0) iorig[spt] = i;
    int j = nbr[i * NSAMP + t];
    jo[spt][t] = j;
    float4 pj = p4[j];
    float4 pc = p4[i];
    float rx = pj.x - pc.x;
    float ry = pj.y - pc.y;
    float rz = pj.z - pc.z;
    #pragma unroll
    for (int c3 = 0; c3 < 3; ++c3) {
      float t2 = rx * pw1[0 * 3 + c3] + ry * pw1[1 * 3 + c3] + rz * pw1[2 * 3 + c3] + pb1[c3];
      t2 = (t2 - pbnm[c3]) * rsqrtf(pbnv[c3] + EPSBN) * pbng[c3] + pbnb[c3];
      q3_s[spt][t][c3] = fmaxf(t2, 0.f);
    }
  }
  __syncthreads();

  const int pt = tid >> 7;
  const int t127 = tid & 127;
  const int g = t127 >> 5;
  const int cg = (t127 & 31) * 8;
  const int brow = iorig[pt];

  float xqv[8], s1v[8], o1v[8], w20v[8], w21v[8], w22v[8], pb2v[8];
  {
    bf16x8 xq8 = *(const bf16x8*)&xqkv[(size_t)brow * 768 + cg];
    #pragma unroll
    for (int u = 0; u < 8; ++u) {
      int c = cg + u;
      xqv[u] = b2f(xq8[u]);
      s1v[u] = sc1[c];
      o1v[u] = of1[c];
      w20v[u] = pw2[c];
      w21v[u] = pw2[256 + c];
      w22v[u] = pw2[512 + c];
      pb2v[u] = pb2[c];
    }
  }

  #pragma unroll
  for (int pass = 0; pass < 4; ++pass) {
    int t = g + pass * 4;
    int k = jo[pt][t];
    float q30 = q3_s[pt][t][0], q31 = q3_s[pt][t][1], q32 = q3_s[pt][t][2];
    bf16x8 xk8 = *(const bf16x8*)&xqkv[(size_t)k * 768 + 256 + cg];
    bf16x8 av;
    #pragma unroll
    for (int u = 0; u < 8; ++u) {
      float prv = q30 * w20v[u] + q31 * w21v[u] + q32 * w22v[u] + pb2v[u];
      float r = b2f(xk8[u]) - xqv[u] + prv;
      av[u] = f2b(fmaxf(r * s1v[u] + o1v[u], 0.f));
    }
    *(bf16x8*)&a_s[pt][t][cg] = av;
  }
  __syncthreads();

  const int w = tid >> 6;
  const int lane = tid & 63;
  const int mpt = w >> 1, hh = w & 1;
  const int nn = lane & 15, q = lane >> 4;
  {
    f32x4 acc = {0.f, 0.f, 0.f, 0.f};
    #pragma unroll
    for (int k0 = 0; k0 < 256; k0 += 32) {
      bf16x8 a = *(const bf16x8*)&a_s[mpt][nn][k0 + q * 8];
      bf16x8 bb = *(const bf16x8*)&l1wp[hh * 4096 + (k0 >> 3) * 128 + q * 128 + nn * 8];
      acc = __builtin_amdgcn_mfma_f32_16x16x32_bf16(a, bb, acc, 0, 0, 0);
    }
    int h = hh * 16 + nn;
    float s2 = bn2g[h] * rsqrtf(bn2v[h] + EPSBN);
    float o2 = bn2b[h] - bn2m[h] * s2;
    float l1bh = l1b[h];
    #pragma unroll
    for (int r = 0; r < 4; ++r)
      h1_s[mpt][q * 4 + r][h] = __float2bfloat16(fmaxf((acc[r] + l1bh) * s2 + o2, 0.f));
  }
  __syncthreads();

  {
    bf16x8 a = *(const bf16x8*)&h1_s[mpt][nn][q * 8];
    bf16x8 bb = *(const bf16x8*)&l2wp[hh * 512 + q * 128 + nn * 8];
    f32x4 z = {0.f, 0.f, 0.f, 0.f};
    f32x4 d = __builtin_amdgcn_mfma_f32_16x16x32_bf16(a, bb, z, 0, 0, 0);
    int h = hh * 16 + nn;
    float l2bh = l2b[h];
    #pragma unroll
    for (int r = 0; r < 4; ++r) w_s[mpt][q * 4 + r][h] = d[r] + l2bh;
  }
  __syncthreads();

  if (tid < 64) {
    int spt = tid >> 5, h = tid & 31;
    float m = -1e30f;
    #pragma unroll
    for (int t = 0; t < NSAMP; ++t) m = fmaxf(m, w_s[spt][t][h]);
    float e[NSAMP];
    float ssum = 0.f;
    #pragma unroll
    for (int t = 0; t < NSAMP; ++t) { e[t] = __expf(w_s[spt][t][h] - m); ssum += e[t]; }
    float inv = 1.f / ssum;
    #pragma unroll
    for (int t = 0; t < NSAMP; ++t) w_s[spt][t][h] = e[t] * inv;
  }
  __syncthreads();

  const int hb = cg & 31;
  float acc8[8];
  #pragma unroll
  for (int u = 0; u < 8; ++u) acc8[u] = 0.f;
  #pragma unroll
  for (int pass = 0; pass < 4; ++pass) {
    int t = g + pass * 4;
    int k = jo[pt][t];
    float q30 = q3_s[pt][t][0], q31 = q3_s[pt][t][1], q32 = q3_s[pt][t][2];
    bf16x8 xv8 = *(const bf16x8*)&xqkv[(size_t)k * 768 + 512 + cg];
    #pragma unroll
    for (int u = 0; u < 8; ++u) {
      float prv = q30 * w20v[u] + q31 * w21v[u] + q32 * w22v[u] + pb2v[u];
      acc8[u] += (b2f(xv8[u]) + prv) * w_s[pt][t][hb + u];
    }
  }
  #pragma unroll
  for (int u = 0; u < 8; ++u) acc8[u] += __shfl_xor(acc8[u], 32, 64);
  if ((lane >> 5) == 0) {
    #pragma unroll
    for (int u = 0; u < 8; ++u) psum[mpt][hh][cg + u] = acc8[u];
  }
  __syncthreads();
  {
    int opt = tid >> 7;
    int c0 = (tid & 127) * 2;
    float v0 = psum[opt][0][c0] + psum[opt][1][c0];
    float v1 = psum[opt][0][c0 + 1] + psum[opt][1][c0 + 1];
    int io = iorig[opt];
    *(float2*)&out[(size_t)io * OUT_C + c0] = make_float2(v0, v1);
  }
}

// ---------------------------------------------------------------- launch
extern "C" void kernel_launch(void* const* d_in, const int* in_sizes, int n_in,
                              void* d_out, int out_size, void* d_ws, size_t ws_size,
                              hipStream_t stream) {
  const float* p    = (const float*)d_in[0];
  const float* x    = (const float*)d_in[1];
  const float* wq   = (const float*)d_in[2];
  const float* bq   = (const float*)d_in[3];
  const float* wk   = (const float*)d_in[4];
  const float* bk   = (const float*)d_in[5];
  const float* wv   = (const float*)d_in[6];
  const float* bv   = (const float*)d_in[7];
  const float* pw1  = (const float*)d_in[8];
  const float* pb1  = (const float*)d_in[9];
  const float* pbng = (const float*)d_in[10];
  const float* pbnb = (const float*)d_in[11];
  const float* pbnm = (const float*)d_in[12];
  const float* pbnv = (const float*)d_in[13];
  const float* pw2  = (const float*)d_in[14];
  const float* pb2  = (const float*)d_in[15];
  const float* bn1g = (const float*)d_in[16];
  const float* bn1b = (const float*)d_in[17];
  const float* bn1m = (const float*)d_in[18];
  const float* bn1v = (const float*)d_in[19];
  const float* l1w  = (const float*)d_in[20];
  const float* l1b  = (const float*)d_in[21];
  const float* bn2g = (const float*)d_in[22];
  const float* bn2b = (const float*)d_in[23];
  const float* bn2m = (const float*)d_in[24];
  const float* bn2v = (const float*)d_in[25];
  const float* l2w  = (const float*)d_in[26];
  const float* l2b  = (const float*)d_in[27];
  float* out = (float*)d_out;

  char* ws = (char*)d_ws;
  float4* p4       = (float4*)(ws + 0x000000);
  float*  biasp    = (float*)(ws + 0x040000);
  int*    cursor   = (int*)(ws + 0x042800);
  int*    cell_st  = (int*)(ws + 0x043000);
  int*    pt_cell  = (int*)(ws + 0x044000);
  float4* sp4      = (float4*)(ws + 0x050000);
  int*    sidx     = (int*)(ws + 0x070000);
  __hip_bfloat16* l1wp = (__hip_bfloat16*)(ws + 0x080000);
  __hip_bfloat16* l2wp = (__hip_bfloat16*)(ws + 0x084000);
  float*  sc1      = (float*)(ws + 0x085000);
  float*  of1      = (float*)(ws + 0x085800);
  int*    rank     = (int*)(ws + 0x088000);
  int*    nbr      = (int*)(ws + 0x090000);
  __hip_bfloat16* Bp   = (__hip_bfloat16*)(ws + 0x110000);
  __hip_bfloat16* xb   = (__hip_bfloat16*)(ws + 0x170000);  // 4MB, ends at 0x570000
  __hip_bfloat16* xqkv = (__hip_bfloat16*)(ws + 0x570000);

  prep_kernel<<<dim3(1024), dim3(256), 0, stream>>>(
      p, x, wq, wk, wv, bq, bk, bv, l1w, l2w, bn1g, bn1b, bn1m, bn1v,
      p4, Bp, biasp, xb, l1wp, l2wp, sc1, of1, cursor, pt_cell);
  scatter_gemm<<<dim3(GEMM_BLKS2 + 16), dim3(512), 0, stream>>>(
      p4, pt_cell, cell_st, cursor, sp4, sidx, rank, xb, Bp, biasp, xqkv);
  knn_grid<<<dim3(NCELL * 2), dim3(256), 0, stream>>>(sp4, sidx, cell_st, nbr);
  fused_pt<<<dim3(N_PTS / 2), dim3(256), 0, stream>>>(
      p4, sidx, xqkv, nbr, pw1, pb1, pbng, pbnb, pbnm, pbnv, pw2, pb2,
      sc1, of1, l1wp, l1b, bn2g, bn2b, bn2m, bn2v, l2wp, l2b, out);
}

// Round 10
// 179.215 us; speedup vs baseline: 1.0986x; 1.0324x over previous
//
#include <hip/hip_runtime.h>
#include <hip/hip_bf16.h>
#include <math.h>

#define N_PTS 8192
#define C_IN  256
#define OUT_C 256
#define NSAMP 16
#define H_W   32
#define EPSBN 1e-5f
#define GDIM  8
#define NCELL (GDIM * GDIM * GDIM)
#define CAPC  768
#define CAP_H 96
#define GEMM_BLKS2 192   // 192 blocks x 8 waves = same 1536 gw as 384 x 4
#define NSTAGE (CAPC / 32)   // 24 staged candidates per lane

typedef short bf16x8 __attribute__((ext_vector_type(8)));
typedef float f32x4  __attribute__((ext_vector_type(4)));

// EXACT arithmetic from the passing rounds: plain expression, default
// compiler contraction, shared by all scans. Do NOT change the rounding.
__device__ __forceinline__ float dist2(const float4 a, const float4 b) {
  float dot = a.x * b.x + a.y * b.y + a.z * b.z;
  return a.w + b.w - 2.0f * dot;
}

__device__ __forceinline__ unsigned long long make_key(float d, int j) {
  unsigned int di = __float_as_uint(d);
  unsigned int ord = ((int)di >= 0) ? (di ^ 0x80000000u) : ~di;
  return ((unsigned long long)ord << 32) | (unsigned int)j;
}

__device__ __forceinline__ void chain_insert(unsigned long long (&ak)[16], unsigned long long key) {
  if (key < ak[0]) {
    #pragma unroll
    for (int s = 0; s < 15; ++s) {
      unsigned long long mn = ak[s] < key ? ak[s] : key;
      unsigned long long nx = ak[s + 1];
      ak[s] = nx > mn ? nx : mn;
    }
    ak[15] = ak[15] < key ? ak[15] : key;
  }
}

// bf16 bit helpers (same rounding as __float2bfloat16 / widening as HW)
__device__ __forceinline__ float b2f(short s) {
  return __uint_as_float(((unsigned int)(unsigned short)s) << 16);
}
__device__ __forceinline__ short f2b(float v) {
  __hip_bfloat16 h = __float2bfloat16(v);
  short s;
  __builtin_memcpy(&s, &h, 2);
  return s;
}

// ---------------------------------------------------------------- prep
__global__ __launch_bounds__(256) void prep_kernel(
    const float* __restrict__ p, const float* __restrict__ x,
    const float* __restrict__ wq, const float* __restrict__ wk, const float* __restrict__ wv,
    const float* __restrict__ bq, const float* __restrict__ bk, const float* __restrict__ bv,
    const float* __restrict__ l1w, const float* __restrict__ l2w,
    const float* __restrict__ bn1g, const float* __restrict__ bn1b,
    const float* __restrict__ bn1m, const float* __restrict__ bn1v,
    float4* __restrict__ p4, __hip_bfloat16* __restrict__ Bp, float* __restrict__ biasp,
    __hip_bfloat16* __restrict__ xb,
    __hip_bfloat16* __restrict__ l1wp, __hip_bfloat16* __restrict__ l2wp,
    float* __restrict__ sc1, float* __restrict__ of1,
    int* __restrict__ cursor, int* __restrict__ pt_cell) {
  int tid = blockIdx.x * blockDim.x + threadIdx.x;
  if (tid < 262144) {  // 8192*256/8 threads, 8 elems each
    const float* xr = &x[(size_t)tid * 8];
    float4 xa = *(const float4*)xr;
    float4 xc = *(const float4*)(xr + 4);
    bf16x8 v;
    v[0] = f2b(xa.x); v[1] = f2b(xa.y); v[2] = f2b(xa.z); v[3] = f2b(xa.w);
    v[4] = f2b(xc.x); v[5] = f2b(xc.y); v[6] = f2b(xc.z); v[7] = f2b(xc.w);
    *(bf16x8*)&xb[(size_t)tid * 8] = v;
  }
  if (tid < 48 * 32 * 16 * 8) {
    int kj = tid & 7, n = (tid >> 3) & 15, kb = (tid >> 7) & 31, nt = tid >> 12;
    int k = kb * 8 + kj, col = nt * 16 + n;
    float v;
    if (col < 256)      v = wq[k * 256 + col];
    else if (col < 512) v = wk[k * 256 + (col - 256)];
    else                v = wv[k * 256 + (col - 512)];
    Bp[tid] = __float2bfloat16(v);
  }
  if (tid < 768) {
    biasp[tid] = tid < 256 ? bq[tid] : (tid < 512 ? bk[tid - 256] : bv[tid - 512]);
  }
  if (tid < 8192) {
    int kj = tid & 7, n = (tid >> 3) & 15, kb = (tid >> 7) & 31, nt = (tid >> 12) & 1;
    int k = kb * 8 + kj, col = nt * 16 + n;
    l1wp[tid] = __float2bfloat16(l1w[k * 32 + col]);
  }
  if (tid < 1024) {
    int kj = tid & 7, n = (tid >> 3) & 15, kb = (tid >> 7) & 3, nt = (tid >> 9) & 1;
    int k = kb * 8 + kj, col = nt * 16 + n;
    l2wp[tid] = __float2bfloat16(l2w[k * 32 + col]);
  }
  if (tid < 256) {
    float s1 = bn1g[tid] * rsqrtf(bn1v[tid] + EPSBN);
    sc1[tid] = s1;
    of1[tid] = bn1b[tid] - bn1m[tid] * s1;
  }
  if (tid < NCELL) cursor[tid] = 0;
  if (tid < N_PTS) {
    float px = p[tid * 3 + 0], py = p[tid * 3 + 1], pz = p[tid * 3 + 2];
    float sq = px * px;
    sq += py * py;
    sq += pz * pz;
    p4[tid] = make_float4(px, py, pz, sq);
    int cx = min(GDIM - 1, max(0, (int)(px * GDIM)));
    int cy = min(GDIM - 1, max(0, (int)(py * GDIM)));
    int cz = min(GDIM - 1, max(0, (int)(pz * GDIM)));
    pt_cell[tid] = (cz * GDIM + cy) * GDIM + cx;
  }
}

// ---------------------------------------------------------------- fused scatter + de-gathered QKV GEMM (R9, measured win)
__global__ __launch_bounds__(512) void scatter_gemm(
    const float4* __restrict__ p4, const int* __restrict__ pt_cell,
    int* __restrict__ cell_start, int* __restrict__ cursor,
    float4* __restrict__ sp4, int* __restrict__ sidx, int* __restrict__ rank,
    const __hip_bfloat16* __restrict__ xb, const __hip_bfloat16* __restrict__ Bp,
    const float* __restrict__ biasp, __hip_bfloat16* __restrict__ xqkv) {
  if (blockIdx.x < GEMM_BLKS2) {
    const int w = threadIdx.x >> 6;          // 0..7
    const int lane = threadIdx.x & 63;
    const int gw = blockIdx.x * 8 + w;       // 0..1535, same set as 384x4
    const int m0 = (gw & 127) * 64;
    const int nt4 = (gw >> 7) * 4;
    const int n = lane & 15, q = lane >> 4;

    f32x4 acc[4][4];
    #pragma unroll
    for (int mi = 0; mi < 4; ++mi)
      #pragma unroll
      for (int ni = 0; ni < 4; ++ni) acc[mi][ni] = (f32x4){0.f, 0.f, 0.f, 0.f};

    for (int k0 = 0; k0 < 256; k0 += 32) {
      bf16x8 af[4], bfr[4];
      #pragma unroll
      for (int mi = 0; mi < 4; ++mi)
        af[mi] = *(const bf16x8*)&xb[(size_t)(m0 + mi * 16 + n) * 256 + k0 + q * 8];
      #pragma unroll
      for (int ni = 0; ni < 4; ++ni)
        bfr[ni] = *(const bf16x8*)&Bp[(size_t)(nt4 + ni) * 4096 + (k0 >> 3) * 128 + q * 128 + n * 8];
      #pragma unroll
      for (int mi = 0; mi < 4; ++mi)
        #pragma unroll
        for (int ni = 0; ni < 4; ++ni)
          acc[mi][ni] = __builtin_amdgcn_mfma_f32_16x16x32_bf16(af[mi], bfr[ni], acc[mi][ni], 0, 0, 0);
    }
    #pragma unroll
    for (int ni = 0; ni < 4; ++ni) {
      int col = (nt4 + ni) * 16 + n;
      float b = biasp[col];
      #pragma unroll
      for (int mi = 0; mi < 4; ++mi)
        #pragma unroll
        for (int r = 0; r < 4; ++r)
          xqkv[(size_t)(m0 + mi * 16 + q * 4 + r) * 768 + col] = __float2bfloat16(acc[mi][ni][r] + b);
    }
    return;
  }

  // ------------------------------ scatter branch
  const int sbid = blockIdx.x - GEMM_BLKS2;
  __shared__ int buf[NCELL];
  const int t = threadIdx.x;
  buf[t] = 0;
  __syncthreads();
  for (int i = t; i < N_PTS; i += 512) atomicAdd(&buf[pt_cell[i]], 1);
  __syncthreads();
  for (int off = 1; off < NCELL; off <<= 1) {
    int add = (t >= off) ? buf[t - off] : 0;
    __syncthreads();
    buf[t] += add;
    __syncthreads();
  }
  if (sbid == 0) {
    cell_start[t + 1] = buf[t];
    if (t == 0) cell_start[0] = 0;
  }
  const int pid = sbid * 512 + t;
  const int c = pt_cell[pid];
  const int start = (c == 0) ? 0 : buf[c - 1];
  const int pos = start + atomicAdd(&cursor[c], 1);
  sp4[pos] = p4[pid];
  sidx[pos] = pid;
  rank[pid] = pos;
}

// ---------------------------------------------------------------- exact grid KNN (R3/R7 structure + register-replay phase 2)
// Phase 1 captures each lane's staged distances in a fully-unrolled
// 24-register array; phase 2 replays from registers (cidx LDS read only
// on the rare d<=d16 hits) instead of re-reading cpos + recomputing
// dist2. Same distance values bit-for-bit, same orders; overflow and
// guard-trigger paths keep the original recompute form.
__global__ __launch_bounds__(256) void knn_grid(
    const float4* __restrict__ sp4, const int* __restrict__ sidx,
    const int* __restrict__ cell_start, int* __restrict__ nbr) {
  const int kbid = blockIdx.x;
  const int cell = kbid >> 1;
  const int sub  = kbid & 1;
  const int cs = cell_start[cell], ce = cell_start[cell + 1];
  if (cs + 8 * sub >= ce) return;   // empty sub: skip staging entirely

  __shared__ float4 cpos[CAPC];
  __shared__ int    cidx[CAPC];
  __shared__ unsigned long long hk_s[8][CAP_H];
  __shared__ unsigned long long okey_s[8][16];
  __shared__ float tv_s[8][64];
  __shared__ int cnt_s[8];
  __shared__ int cell_s0_s[27];
  __shared__ int len_s[27];
  __shared__ int pref_s[28];
  __shared__ int nc_s, total_s;

  const int tid = threadIdx.x;
  const int hcx = cell & 7, hcy = (cell >> 3) & 7, hcz = cell >> 6;

  const int ax0 = max(hcx - 1, 0), ax1 = min(hcx + 1, GDIM - 1);
  const int ay0 = max(hcy - 1, 0), ay1 = min(hcy + 1, GDIM - 1);
  const int az0 = max(hcz - 1, 0), az1 = min(hcz + 1, GDIM - 1);
  const int nx = ax1 - ax0 + 1, ny = ay1 - ay0 + 1, nz = az1 - az0 + 1;
  const int nbc = nx * ny * nz;

  if (tid < nbc) {
    int cx = ax0 + tid % nx;
    int cy = ay0 + (tid / nx) % ny;
    int cz = az0 + tid / (nx * ny);
    int cc = (cz * GDIM + cy) * GDIM + cx;
    int s0 = cell_start[cc];
    cell_s0_s[tid] = s0;
    len_s[tid] = cell_start[cc + 1] - s0;
  }
  __syncthreads();
  if (tid == 0) {
    int off = 0;
    for (int m = 0; m < nbc; ++m) { pref_s[m] = off; off += len_s[m]; }
    pref_s[nbc] = off;
    nc_s = nbc;
    total_s = off;
  }
  __syncthreads();
  const int nc = nc_s, total = total_s;
  const int tstage = total < CAPC ? total : CAPC;

  // staging: one 32-lane group per neighbor cell, coalesced copy
  {
    const int grp = tid >> 5, ln = tid & 31;
    for (int m = grp; m < nbc; m += 8) {
      int base = pref_s[m], src = cell_s0_s[m];
      int lim = min(len_s[m], CAPC - base);
      for (int i = ln; i < lim; i += 32) {
        cpos[base + i] = sp4[src + i];
        cidx[base + i] = sidx[src + i];
      }
    }
  }
  __syncthreads();

  const int ptl = tid >> 5, slice = tid & 31;

  for (int p0 = cs + 8 * sub; p0 < ce; p0 += 16) {
    const int np = min(8, ce - p0);
    const bool pok = ptl < np;
    const int ld = pok ? (p0 + ptl) : cs;
    const float4 pi = sp4[ld];
    const int orig = sidx[ld];

    if (tid < 8) cnt_s[tid] = 0;
    if (tid < 128) okey_s[tid >> 4][tid & 15] = ~0ULL;
    __syncthreads();

    // phase 1: per-slice 2 smallest distances, capturing staged distances
    // in registers (fully unrolled -> stays in VGPRs, not scratch)
    float dv[NSTAGE];
    float t0 = 3.0e38f, t1 = 3.0e38f;  // t0 <= t1
    #pragma unroll
    for (int j = 0; j < NSTAGE; ++j) {
      int idx = slice + j * 32;
      float d = 3.0e38f;
      if (idx < tstage) d = dist2(pi, cpos[idx]);
      dv[j] = d;
      if (d < t1) {
        if (d < t0) { t1 = t0; t0 = d; } else { t1 = d; }
      }
    }
    for (int idx = slice + CAPC; idx < total; idx += 32) {   // overflow (~never)
      int c = 0;
      while (c + 1 < nc && pref_s[c + 1] <= idx) ++c;
      float d = dist2(pi, sp4[cell_s0_s[c] + (idx - pref_s[c])]);
      if (d < t1) {
        if (d < t0) { t1 = t0; t0 = d; } else { t1 = d; }
      }
    }
    tv_s[ptl][slice * 2]     = t0;
    tv_s[ptl][slice * 2 + 1] = t1;
    __syncthreads();

    // 16th-smallest of the 64-value union via strict-rank (broadcast reads)
    int r0 = 0, r1 = 0;
    #pragma unroll 8
    for (int j = 0; j < 64; ++j) {
      float wv = tv_s[ptl][j];
      r0 += (wv < t0) ? 1 : 0;
      r1 += (wv < t1) ? 1 : 0;
    }
    float cand = fmaxf(r0 <= 15 ? t0 : -3.0e38f, r1 <= 15 ? t1 : -3.0e38f);
    cand = fmaxf(cand, __shfl_xor(cand, 1, 64));
    cand = fmaxf(cand, __shfl_xor(cand, 2, 64));
    cand = fmaxf(cand, __shfl_xor(cand, 4, 64));
    cand = fmaxf(cand, __shfl_xor(cand, 8, 64));
    cand = fmaxf(cand, __shfl_xor(cand, 16, 64));
    const float d16 = cand;   // >= true d16; #(d<=d16) >= 16 when total>=16

    // conservative guard box from d16 (contains the true 16-NN ball)
    const float rg = sqrtf(fmaxf(d16, 0.f)) * 1.001f + 1e-4f;
    const int lx = (int)fminf(fmaxf(floorf((pi.x - rg) * GDIM), 0.f), (float)(GDIM - 1));
    const int ux = (int)fminf(fmaxf(floorf((pi.x + rg) * GDIM), 0.f), (float)(GDIM - 1));
    const int ly = (int)fminf(fmaxf(floorf((pi.y - rg) * GDIM), 0.f), (float)(GDIM - 1));
    const int uy = (int)fminf(fmaxf(floorf((pi.y + rg) * GDIM), 0.f), (float)(GDIM - 1));
    const int lz = (int)fminf(fmaxf(floorf((pi.z - rg) * GDIM), 0.f), (float)(GDIM - 1));
    const int uz = (int)fminf(fmaxf(floorf((pi.z + rg) * GDIM), 0.f), (float)(GDIM - 1));
    const bool trigger = (lx < ax0 || ux > ax1 || ly < ay0 || uy > ay1 || lz < az0 || uz > az1);

    // phase 2: register replay -- LDS touched only on hits
    if (pok) {
      #pragma unroll
      for (int j = 0; j < NSTAGE; ++j) {
        int idx = slice + j * 32;
        float d = dv[j];
        if (idx < tstage && d <= d16) {
          int pos = atomicAdd(&cnt_s[ptl], 1);
          if (pos < CAP_H) hk_s[ptl][pos] = make_key(d, cidx[idx]);
        }
      }
      for (int idx = slice + CAPC; idx < total; idx += 32) {   // overflow (~never)
        int c = 0;
        while (c + 1 < nc && pref_s[c + 1] <= idx) ++c;
        int g = cell_s0_s[c] + (idx - pref_s[c]);
        float d = dist2(pi, sp4[g]);
        if (d <= d16) {
          int pos = atomicAdd(&cnt_s[ptl], 1);
          if (pos < CAP_H) hk_s[ptl][pos] = make_key(d, sidx[g]);
        }
      }
      if (trigger) {
        for (int cz = lz; cz <= uz; ++cz)
          for (int cy = ly; cy <= uy; ++cy)
            for (int cx = lx; cx <= ux; ++cx) {
              if (cx >= ax0 && cx <= ax1 && cy >= ay0 && cy <= ay1 && cz >= az0 && cz <= az1)
                continue;
              int cc = (cz * GDIM + cy) * GDIM + cx;
              int s0 = cell_start[cc], e0 = cell_start[cc + 1];
              for (int k = s0 + slice; k < e0; k += 32) {
                float d = dist2(pi, sp4[k]);
                if (d <= d16) {
                  int pos = atomicAdd(&cnt_s[ptl], 1);
                  if (pos < CAP_H) hk_s[ptl][pos] = make_key(d, sidx[k]);
                }
              }
            }
      }
    }
    __syncthreads();

    const int cntr = cnt_s[ptl];
    const bool overflow = cntr > CAP_H;   // needs 97+ candidates <= d16 (~never)
    const int cnt = overflow ? 0 : cntr;

    // exact rank-select of top-16 among collected keys
    if (pok) {
      for (int i = slice; i < cnt; i += 32) {
        unsigned long long key = hk_s[ptl][i];
        int rk = 0;
        for (int j = 0; j < cnt; ++j) rk += (hk_s[ptl][j] < key) ? 1 : 0;
        if (rk < 16) okey_s[ptl][rk] = key;
      }
    }
    __syncthreads();

    if (!overflow) {
      if (pok && slice < 16) {
        unsigned long long key = okey_s[ptl][15 - slice];
        nbr[orig * NSAMP + slice] = (int)(key & 0xFFFFFFFFu);
      }
    } else if (pok && slice == 0) {
      // exact serial fallback (~never taken)
      unsigned long long akm[16];
      #pragma unroll
      for (int s = 0; s < 16; ++s) akm[s] = ~0ULL;
      for (int idx2 = 0; idx2 < total; ++idx2) {
        float4 q; int qi;
        if (idx2 < CAPC) { q = cpos[idx2]; qi = cidx[idx2]; }
        else {
          int c = 0;
          while (c + 1 < nc && pref_s[c + 1] <= idx2) ++c;
          int g = cell_s0_s[c] + (idx2 - pref_s[c]);
          q = sp4[g]; qi = sidx[g];
        }
        chain_insert(akm, make_key(dist2(pi, q), qi));
      }
      float r;
      if (akm[0] == ~0ULL) r = 1e9f;
      else {
        unsigned int ord = (unsigned int)(akm[0] >> 32);
        unsigned int di = (ord & 0x80000000u) ? (ord ^ 0x80000000u) : ~ord;
        float dd = __uint_as_float(di);
        r = sqrtf(fmaxf(dd, 0.f)) * 1.001f + 1e-4f;
      }
      int flx = (int)fminf(fmaxf(floorf((pi.x - r) * GDIM), 0.f), (float)(GDIM - 1));
      int fux = (int)fminf(fmaxf(floorf((pi.x + r) * GDIM), 0.f), (float)(GDIM - 1));
      int fly = (int)fminf(fmaxf(floorf((pi.y - r) * GDIM), 0.f), (float)(GDIM - 1));
      int fuy = (int)fminf(fmaxf(floorf((pi.y + r) * GDIM), 0.f), (float)(GDIM - 1));
      int flz = (int)fminf(fmaxf(floorf((pi.z - r) * GDIM), 0.f), (float)(GDIM - 1));
      int fuz = (int)fminf(fmaxf(floorf((pi.z + r) * GDIM), 0.f), (float)(GDIM - 1));
      for (int cz = flz; cz <= fuz; ++cz)
        for (int cy = fly; cy <= fuy; ++cy)
          for (int cx = flx; cx <= fux; ++cx) {
            if (cx >= ax0 && cx <= ax1 && cy >= ay0 && cy <= ay1 && cz >= az0 && cz <= az1)
              continue;
            int cc = (cz * GDIM + cy) * GDIM + cx;
            int s0 = cell_start[cc], e0 = cell_start[cc + 1];
            for (int k = s0; k < e0; ++k)
              chain_insert(akm, make_key(dist2(pi, sp4[k]), sidx[k]));
          }
      #pragma unroll
      for (int s = 0; s < 16; ++s) nbr[orig * NSAMP + s] = (int)(akm[s] & 0xFFFFFFFFu);
    }
    __syncthreads();
  }
}

// ---------------------------------------------------------------- fused per-point transform: 2 points/block, all-wave MFMA
// xqkv is ORIGINAL-order. Positions read from p4 directly.
__global__ __launch_bounds__(256) void fused_pt(
    const float4* __restrict__ p4, const int* __restrict__ sidx,
    const __hip_bfloat16* __restrict__ xqkv, const int* __restrict__ nbr,
    const float* __restrict__ pw1, const float* __restrict__ pb1,
    const float* __restrict__ pbng, const float* __restrict__ pbnb,
    const float* __restrict__ pbnm, const float* __restrict__ pbnv,
    const float* __restrict__ pw2, const float* __restrict__ pb2,
    const float* __restrict__ sc1, const float* __restrict__ of1,
    const __hip_bfloat16* __restrict__ l1wp, const float* __restrict__ l1b,
    const float* __restrict__ bn2g, const float* __restrict__ bn2b,
    const float* __restrict__ bn2m, const float* __restrict__ bn2v,
    const __hip_bfloat16* __restrict__ l2wp, const float* __restrict__ l2b,
    float* __restrict__ out) {
  __shared__ __align__(16) __hip_bfloat16 a_s[2][NSAMP][264];
  __shared__ __align__(16) __hip_bfloat16 h1_s[2][NSAMP][40];
  __shared__ float w_s[2][NSAMP][33];
  __shared__ float q3_s[2][NSAMP][4];
  __shared__ int jo[2][NSAMP];
  __shared__ float psum[2][2][264];
  __shared__ int iorig[2];

  const int b0 = blockIdx.x * 2;
  const int tid = threadIdx.x;

  if (tid < 32) {
    int spt = tid >> 4, t = tid & 15;
    int b = b0 + spt;
    int i = sidx[b];
    if (t == 0) iorig[spt] = i;
    int j = nbr[i * NSAMP + t];
    jo[spt][t] = j;
    float4 pj = p4[j];
    float4 pc = p4[i];
    float rx = pj.x - pc.x;
    float ry = pj.y - pc.y;
    float rz = pj.z - pc.z;
    #pragma unroll
    for (int c3 = 0; c3 < 3; ++c3) {
      float t2 = rx * pw1[0 * 3 + c3] + ry * pw1[1 * 3 + c3] + rz * pw1[2 * 3 + c3] + pb1[c3];
      t2 = (t2 - pbnm[c3]) * rsqrtf(pbnv[c3] + EPSBN) * pbng[c3] + pbnb[c3];
      q3_s[spt][t][c3] = fmaxf(t2, 0.f);
    }
  }
  __syncthreads();

  const int pt = tid >> 7;
  const int t127 = tid & 127;
  const int g = t127 >> 5;
  const int cg = (t127 & 31) * 8;
  const int brow = iorig[pt];

  float xqv[8], s1v[8], o1v[8], w20v[8], w21v[8], w22v[8], pb2v[8];
  {
    bf16x8 xq8 = *(const bf16x8*)&xqkv[(size_t)brow * 768 + cg];
    #pragma unroll
    for (int u = 0; u < 8; ++u) {
      int c = cg + u;
      xqv[u] = b2f(xq8[u]);
      s1v[u] = sc1[c];
      o1v[u] = of1[c];
      w20v[u] = pw2[c];
      w21v[u] = pw2[256 + c];
      w22v[u] = pw2[512 + c];
      pb2v[u] = pb2[c];
    }
  }

  #pragma unroll
  for (int pass = 0; pass < 4; ++pass) {
    int t = g + pass * 4;
    int k = jo[pt][t];
    float q30 = q3_s[pt][t][0], q31 = q3_s[pt][t][1], q32 = q3_s[pt][t][2];
    bf16x8 xk8 = *(const bf16x8*)&xqkv[(size_t)k * 768 + 256 + cg];
    bf16x8 av;
    #pragma unroll
    for (int u = 0; u < 8; ++u) {
      float prv = q30 * w20v[u] + q31 * w21v[u] + q32 * w22v[u] + pb2v[u];
      float r = b2f(xk8[u]) - xqv[u] + prv;
      av[u] = f2b(fmaxf(r * s1v[u] + o1v[u], 0.f));
    }
    *(bf16x8*)&a_s[pt][t][cg] = av;
  }
  __syncthreads();

  const int w = tid >> 6;
  const int lane = tid & 63;
  const int mpt = w >> 1, hh = w & 1;
  const int nn = lane & 15, q = lane >> 4;
  {
    f32x4 acc = {0.f, 0.f, 0.f, 0.f};
    #pragma unroll
    for (int k0 = 0; k0 < 256; k0 += 32) {
      bf16x8 a = *(const bf16x8*)&a_s[mpt][nn][k0 + q * 8];
      bf16x8 bb = *(const bf16x8*)&l1wp[hh * 4096 + (k0 >> 3) * 128 + q * 128 + nn * 8];
      acc = __builtin_amdgcn_mfma_f32_16x16x32_bf16(a, bb, acc, 0, 0, 0);
    }
    int h = hh * 16 + nn;
    float s2 = bn2g[h] * rsqrtf(bn2v[h] + EPSBN);
    float o2 = bn2b[h] - bn2m[h] * s2;
    float l1bh = l1b[h];
    #pragma unroll
    for (int r = 0; r < 4; ++r)
      h1_s[mpt][q * 4 + r][h] = __float2bfloat16(fmaxf((acc[r] + l1bh) * s2 + o2, 0.f));
  }
  __syncthreads();

  {
    bf16x8 a = *(const bf16x8*)&h1_s[mpt][nn][q * 8];
    bf16x8 bb = *(const bf16x8*)&l2wp[hh * 512 + q * 128 + nn * 8];
    f32x4 z = {0.f, 0.f, 0.f, 0.f};
    f32x4 d = __builtin_amdgcn_mfma_f32_16x16x32_bf16(a, bb, z, 0, 0, 0);
    int h = hh * 16 + nn;
    float l2bh = l2b[h];
    #pragma unroll
    for (int r = 0; r < 4; ++r) w_s[mpt][q * 4 + r][h] = d[r] + l2bh;
  }
  __syncthreads();

  if (tid < 64) {
    int spt = tid >> 5, h = tid & 31;
    float m = -1e30f;
    #pragma unroll
    for (int t = 0; t < NSAMP; ++t) m = fmaxf(m, w_s[spt][t][h]);
    float e[NSAMP];
    float ssum = 0.f;
    #pragma unroll
    for (int t = 0; t < NSAMP; ++t) { e[t] = __expf(w_s[spt][t][h] - m); ssum += e[t]; }
    float inv = 1.f / ssum;
    #pragma unroll
    for (int t = 0; t < NSAMP; ++t) w_s[spt][t][h] = e[t] * inv;
  }
  __syncthreads();

  const int hb = cg & 31;
  float acc8[8];
  #pragma unroll
  for (int u = 0; u < 8; ++u) acc8[u] = 0.f;
  #pragma unroll
  for (int pass = 0; pass < 4; ++pass) {
    int t = g + pass * 4;
    int k = jo[pt][t];
    float q30 = q3_s[pt][t][0], q31 = q3_s[pt][t][1], q32 = q3_s[pt][t][2];
    bf16x8 xv8 = *(const bf16x8*)&xqkv[(size_t)k * 768 + 512 + cg];
    #pragma unroll
    for (int u = 0; u < 8; ++u) {
      float prv = q30 * w20v[u] + q31 * w21v[u] + q32 * w22v[u] + pb2v[u];
      acc8[u] += (b2f(xv8[u]) + prv) * w_s[pt][t][hb + u];
    }
  }
  #pragma unroll
  for (int u = 0; u < 8; ++u) acc8[u] += __shfl_xor(acc8[u], 32, 64);
  if ((lane >> 5) == 0) {
    #pragma unroll
    for (int u = 0; u < 8; ++u) psum[mpt][hh][cg + u] = acc8[u];
  }
  __syncthreads();
  {
    int opt = tid >> 7;
    int c0 = (tid & 127) * 2;
    float v0 = psum[opt][0][c0] + psum[opt][1][c0];
    float v1 = psum[opt][0][c0 + 1] + psum[opt][1][c0 + 1];
    int io = iorig[opt];
    *(float2*)&out[(size_t)io * OUT_C + c0] = make_float2(v0, v1);
  }
}

// ---------------------------------------------------------------- launch
extern "C" void kernel_launch(void* const* d_in, const int* in_sizes, int n_in,
                              void* d_out, int out_size, void* d_ws, size_t ws_size,
                              hipStream_t stream) {
  const float* p    = (const float*)d_in[0];
  const float* x    = (const float*)d_in[1];
  const float* wq   = (const float*)d_in[2];
  const float* bq   = (const float*)d_in[3];
  const float* wk   = (const float*)d_in[4];
  const float* bk   = (const float*)d_in[5];
  const float* wv   = (const float*)d_in[6];
  const float* bv   = (const float*)d_in[7];
  const float* pw1  = (const float*)d_in[8];
  const float* pb1  = (const float*)d_in[9];
  const float* pbng = (const float*)d_in[10];
  const float* pbnb = (const float*)d_in[11];
  const float* pbnm = (const float*)d_in[12];
  const float* pbnv = (const float*)d_in[13];
  const float* pw2  = (const float*)d_in[14];
  const float* pb2  = (const float*)d_in[15];
  const float* bn1g = (const float*)d_in[16];
  const float* bn1b = (const float*)d_in[17];
  const float* bn1m = (const float*)d_in[18];
  const float* bn1v = (const float*)d_in[19];
  const float* l1w  = (const float*)d_in[20];
  const float* l1b  = (const float*)d_in[21];
  const float* bn2g = (const float*)d_in[22];
  const float* bn2b = (const float*)d_in[23];
  const float* bn2m = (const float*)d_in[24];
  const float* bn2v = (const float*)d_in[25];
  const float* l2w  = (const float*)d_in[26];
  const float* l2b  = (const float*)d_in[27];
  float* out = (float*)d_out;

  char* ws = (char*)d_ws;
  float4* p4       = (float4*)(ws + 0x000000);
  float*  biasp    = (float*)(ws + 0x040000);
  int*    cursor   = (int*)(ws + 0x042800);
  int*    cell_st  = (int*)(ws + 0x043000);
  int*    pt_cell  = (int*)(ws + 0x044000);
  float4* sp4      = (float4*)(ws + 0x050000);
  int*    sidx     = (int*)(ws + 0x070000);
  __hip_bfloat16* l1wp = (__hip_bfloat16*)(ws + 0x080000);
  __hip_bfloat16* l2wp = (__hip_bfloat16*)(ws + 0x084000);
  float*  sc1      = (float*)(ws + 0x085000);
  float*  of1      = (float*)(ws + 0x085800);
  int*    rank     = (int*)(ws + 0x088000);
  int*    nbr      = (int*)(ws + 0x090000);
  __hip_bfloat16* Bp   = (__hip_bfloat16*)(ws + 0x110000);
  __hip_bfloat16* xb   = (__hip_bfloat16*)(ws + 0x170000);  // 4MB, ends at 0x570000
  __hip_bfloat16* xqkv = (__hip_bfloat16*)(ws + 0x570000);

  prep_kernel<<<dim3(1024), dim3(256), 0, stream>>>(
      p, x, wq, wk, wv, bq, bk, bv, l1w, l2w, bn1g, bn1b, bn1m, bn1v,
      p4, Bp, biasp, xb, l1wp, l2wp, sc1, of1, cursor, pt_cell);
  scatter_gemm<<<dim3(GEMM_BLKS2 + 16), dim3(512), 0, stream>>>(
      p4, pt_cell, cell_st, cursor, sp4, sidx, rank, xb, Bp, biasp, xqkv);
  knn_grid<<<dim3(NCELL * 2), dim3(256), 0, stream>>>(sp4, sidx, cell_st, nbr);
  fused_pt<<<dim3(N_PTS / 2), dim3(256), 0, stream>>>(
      p4, sidx, xqkv, nbr, pw1, pb1, pbng, pbnb, pbnm, pbnv, pw2, pb2,
      sc1, of1, l1wp, l1b, bn2g, bn2b, bn2m, bn2v, l2wp, l2b, out);
}

// Round 11
// 178.537 us; speedup vs baseline: 1.1028x; 1.0038x over previous
//
#include <hip/hip_runtime.h>
#include <hip/hip_bf16.h>
#include <math.h>

#define N_PTS 8192
#define C_IN  256
#define OUT_C 256
#define NSAMP 16
#define H_W   32
#define EPSBN 1e-5f
#define GDIM  8
#define NCELL (GDIM * GDIM * GDIM)
#define CAPC  768
#define CAP_H 96
#define GEMM_BLKS2 192   // 192 blocks x 8 waves = same 1536 gw as 384 x 4
#define NSTAGE (CAPC / 32)   // 24 staged candidates per lane

typedef short bf16x8 __attribute__((ext_vector_type(8)));
typedef float f32x4  __attribute__((ext_vector_type(4)));

// EXACT arithmetic from the passing rounds: plain expression, default
// compiler contraction, shared by all scans. Do NOT change the rounding.
__device__ __forceinline__ float dist2(const float4 a, const float4 b) {
  float dot = a.x * b.x + a.y * b.y + a.z * b.z;
  return a.w + b.w - 2.0f * dot;
}

__device__ __forceinline__ unsigned long long make_key(float d, int j) {
  unsigned int di = __float_as_uint(d);
  unsigned int ord = ((int)di >= 0) ? (di ^ 0x80000000u) : ~di;
  return ((unsigned long long)ord << 32) | (unsigned int)j;
}

__device__ __forceinline__ void chain_insert(unsigned long long (&ak)[16], unsigned long long key) {
  if (key < ak[0]) {
    #pragma unroll
    for (int s = 0; s < 15; ++s) {
      unsigned long long mn = ak[s] < key ? ak[s] : key;
      unsigned long long nx = ak[s + 1];
      ak[s] = nx > mn ? nx : mn;
    }
    ak[15] = ak[15] < key ? ak[15] : key;
  }
}

// bf16 bit helpers (same rounding as __float2bfloat16 / widening as HW)
__device__ __forceinline__ float b2f(short s) {
  return __uint_as_float(((unsigned int)(unsigned short)s) << 16);
}
__device__ __forceinline__ short f2b(float v) {
  __hip_bfloat16 h = __float2bfloat16(v);
  short s;
  __builtin_memcpy(&s, &h, 2);
  return s;
}

// ---------------------------------------------------------------- prep
__global__ __launch_bounds__(256) void prep_kernel(
    const float* __restrict__ p, const float* __restrict__ x,
    const float* __restrict__ wq, const float* __restrict__ wk, const float* __restrict__ wv,
    const float* __restrict__ bq, const float* __restrict__ bk, const float* __restrict__ bv,
    const float* __restrict__ l1w, const float* __restrict__ l2w,
    const float* __restrict__ bn1g, const float* __restrict__ bn1b,
    const float* __restrict__ bn1m, const float* __restrict__ bn1v,
    float4* __restrict__ p4, __hip_bfloat16* __restrict__ Bp, float* __restrict__ biasp,
    __hip_bfloat16* __restrict__ xb,
    __hip_bfloat16* __restrict__ l1wp, __hip_bfloat16* __restrict__ l2wp,
    float* __restrict__ sc1, float* __restrict__ of1,
    int* __restrict__ cursor, int* __restrict__ pt_cell) {
  int tid = blockIdx.x * blockDim.x + threadIdx.x;
  if (tid < 262144) {  // 8192*256/8 threads, 8 elems each
    const float* xr = &x[(size_t)tid * 8];
    float4 xa = *(const float4*)xr;
    float4 xc = *(const float4*)(xr + 4);
    bf16x8 v;
    v[0] = f2b(xa.x); v[1] = f2b(xa.y); v[2] = f2b(xa.z); v[3] = f2b(xa.w);
    v[4] = f2b(xc.x); v[5] = f2b(xc.y); v[6] = f2b(xc.z); v[7] = f2b(xc.w);
    *(bf16x8*)&xb[(size_t)tid * 8] = v;
  }
  if (tid < 48 * 32 * 16 * 8) {
    int kj = tid & 7, n = (tid >> 3) & 15, kb = (tid >> 7) & 31, nt = tid >> 12;
    int k = kb * 8 + kj, col = nt * 16 + n;
    float v;
    if (col < 256)      v = wq[k * 256 + col];
    else if (col < 512) v = wk[k * 256 + (col - 256)];
    else                v = wv[k * 256 + (col - 512)];
    Bp[tid] = __float2bfloat16(v);
  }
  if (tid < 768) {
    biasp[tid] = tid < 256 ? bq[tid] : (tid < 512 ? bk[tid - 256] : bv[tid - 512]);
  }
  if (tid < 8192) {
    int kj = tid & 7, n = (tid >> 3) & 15, kb = (tid >> 7) & 31, nt = (tid >> 12) & 1;
    int k = kb * 8 + kj, col = nt * 16 + n;
    l1wp[tid] = __float2bfloat16(l1w[k * 32 + col]);
  }
  if (tid < 1024) {
    int kj = tid & 7, n = (tid >> 3) & 15, kb = (tid >> 7) & 3, nt = (tid >> 9) & 1;
    int k = kb * 8 + kj, col = nt * 16 + n;
    l2wp[tid] = __float2bfloat16(l2w[k * 32 + col]);
  }
  if (tid < 256) {
    float s1 = bn1g[tid] * rsqrtf(bn1v[tid] + EPSBN);
    sc1[tid] = s1;
    of1[tid] = bn1b[tid] - bn1m[tid] * s1;
  }
  if (tid < NCELL) cursor[tid] = 0;
  if (tid < N_PTS) {
    float px = p[tid * 3 + 0], py = p[tid * 3 + 1], pz = p[tid * 3 + 2];
    float sq = px * px;
    sq += py * py;
    sq += pz * pz;
    p4[tid] = make_float4(px, py, pz, sq);
    int cx = min(GDIM - 1, max(0, (int)(px * GDIM)));
    int cy = min(GDIM - 1, max(0, (int)(py * GDIM)));
    int cz = min(GDIM - 1, max(0, (int)(pz * GDIM)));
    pt_cell[tid] = (cz * GDIM + cy) * GDIM + cx;
  }
}

// ---------------------------------------------------------------- fused scatter + de-gathered QKV GEMM (R9, measured win)
__global__ __launch_bounds__(512) void scatter_gemm(
    const float4* __restrict__ p4, const int* __restrict__ pt_cell,
    int* __restrict__ cell_start, int* __restrict__ cursor,
    float4* __restrict__ sp4, int* __restrict__ sidx, int* __restrict__ rank,
    const __hip_bfloat16* __restrict__ xb, const __hip_bfloat16* __restrict__ Bp,
    const float* __restrict__ biasp, __hip_bfloat16* __restrict__ xqkv) {
  if (blockIdx.x < GEMM_BLKS2) {
    const int w = threadIdx.x >> 6;          // 0..7
    const int lane = threadIdx.x & 63;
    const int gw = blockIdx.x * 8 + w;       // 0..1535, same set as 384x4
    const int m0 = (gw & 127) * 64;
    const int nt4 = (gw >> 7) * 4;
    const int n = lane & 15, q = lane >> 4;

    f32x4 acc[4][4];
    #pragma unroll
    for (int mi = 0; mi < 4; ++mi)
      #pragma unroll
      for (int ni = 0; ni < 4; ++ni) acc[mi][ni] = (f32x4){0.f, 0.f, 0.f, 0.f};

    for (int k0 = 0; k0 < 256; k0 += 32) {
      bf16x8 af[4], bfr[4];
      #pragma unroll
      for (int mi = 0; mi < 4; ++mi)
        af[mi] = *(const bf16x8*)&xb[(size_t)(m0 + mi * 16 + n) * 256 + k0 + q * 8];
      #pragma unroll
      for (int ni = 0; ni < 4; ++ni)
        bfr[ni] = *(const bf16x8*)&Bp[(size_t)(nt4 + ni) * 4096 + (k0 >> 3) * 128 + q * 128 + n * 8];
      #pragma unroll
      for (int mi = 0; mi < 4; ++mi)
        #pragma unroll
        for (int ni = 0; ni < 4; ++ni)
          acc[mi][ni] = __builtin_amdgcn_mfma_f32_16x16x32_bf16(af[mi], bfr[ni], acc[mi][ni], 0, 0, 0);
    }
    #pragma unroll
    for (int ni = 0; ni < 4; ++ni) {
      int col = (nt4 + ni) * 16 + n;
      float b = biasp[col];
      #pragma unroll
      for (int mi = 0; mi < 4; ++mi)
        #pragma unroll
        for (int r = 0; r < 4; ++r)
          xqkv[(size_t)(m0 + mi * 16 + q * 4 + r) * 768 + col] = __float2bfloat16(acc[mi][ni][r] + b);
    }
    return;
  }

  // ------------------------------ scatter branch
  const int sbid = blockIdx.x - GEMM_BLKS2;
  __shared__ int buf[NCELL];
  const int t = threadIdx.x;
  buf[t] = 0;
  __syncthreads();
  for (int i = t; i < N_PTS; i += 512) atomicAdd(&buf[pt_cell[i]], 1);
  __syncthreads();
  for (int off = 1; off < NCELL; off <<= 1) {
    int add = (t >= off) ? buf[t - off] : 0;
    __syncthreads();
    buf[t] += add;
    __syncthreads();
  }
  if (sbid == 0) {
    cell_start[t + 1] = buf[t];
    if (t == 0) cell_start[0] = 0;
  }
  const int pid = sbid * 512 + t;
  const int c = pt_cell[pid];
  const int start = (c == 0) ? 0 : buf[c - 1];
  const int pos = start + atomicAdd(&cursor[c], 1);
  sp4[pos] = p4[pid];
  sidx[pos] = pid;
  rank[pid] = pos;
}

// ---------------------------------------------------------------- exact grid KNN (R10 structure, barrier-free iterations)
// All per-iteration LDS (cnt_s/hk_s/okey_s/tv_s) is [ptl]-indexed and each
// 32-lane group lives inside ONE wave (groups 2w,2w+1 in wave w; shfl masks
// <=16 stay within each 32-lane half). With the init made group-local
// (slice==0 / slice<16), there are NO cross-wave LDS deps inside the loop,
// so all 5 per-iteration __syncthreads are removed. Same-array LDS accesses
// are may-alias -> compiler preserves in-wave order + inserts lgkmcnt.
// Staging (cpos/cidx, block-wide read-only) keeps its barriers.
__global__ __launch_bounds__(256) void knn_grid(
    const float4* __restrict__ sp4, const int* __restrict__ sidx,
    const int* __restrict__ cell_start, int* __restrict__ nbr) {
  const int kbid = blockIdx.x;
  const int cell = kbid >> 1;
  const int sub  = kbid & 1;
  const int cs = cell_start[cell], ce = cell_start[cell + 1];
  if (cs + 8 * sub >= ce) return;   // empty sub: skip staging entirely

  __shared__ float4 cpos[CAPC];
  __shared__ int    cidx[CAPC];
  __shared__ unsigned long long hk_s[8][CAP_H];
  __shared__ unsigned long long okey_s[8][16];
  __shared__ float tv_s[8][64];
  __shared__ int cnt_s[8];
  __shared__ int cell_s0_s[27];
  __shared__ int len_s[27];
  __shared__ int pref_s[28];
  __shared__ int nc_s, total_s;

  const int tid = threadIdx.x;
  const int hcx = cell & 7, hcy = (cell >> 3) & 7, hcz = cell >> 6;

  const int ax0 = max(hcx - 1, 0), ax1 = min(hcx + 1, GDIM - 1);
  const int ay0 = max(hcy - 1, 0), ay1 = min(hcy + 1, GDIM - 1);
  const int az0 = max(hcz - 1, 0), az1 = min(hcz + 1, GDIM - 1);
  const int nx = ax1 - ax0 + 1, ny = ay1 - ay0 + 1, nz = az1 - az0 + 1;
  const int nbc = nx * ny * nz;

  if (tid < nbc) {
    int cx = ax0 + tid % nx;
    int cy = ay0 + (tid / nx) % ny;
    int cz = az0 + tid / (nx * ny);
    int cc = (cz * GDIM + cy) * GDIM + cx;
    int s0 = cell_start[cc];
    cell_s0_s[tid] = s0;
    len_s[tid] = cell_start[cc + 1] - s0;
  }
  __syncthreads();
  if (tid == 0) {
    int off = 0;
    for (int m = 0; m < nbc; ++m) { pref_s[m] = off; off += len_s[m]; }
    pref_s[nbc] = off;
    nc_s = nbc;
    total_s = off;
  }
  __syncthreads();
  const int nc = nc_s, total = total_s;
  const int tstage = total < CAPC ? total : CAPC;

  // staging: one 32-lane group per neighbor cell, coalesced copy
  {
    const int grp = tid >> 5, ln = tid & 31;
    for (int m = grp; m < nbc; m += 8) {
      int base = pref_s[m], src = cell_s0_s[m];
      int lim = min(len_s[m], CAPC - base);
      for (int i = ln; i < lim; i += 32) {
        cpos[base + i] = sp4[src + i];
        cidx[base + i] = sidx[src + i];
      }
    }
  }
  __syncthreads();

  const int ptl = tid >> 5, slice = tid & 31;

  for (int p0 = cs + 8 * sub; p0 < ce; p0 += 16) {
    const int np = min(8, ce - p0);
    const bool pok = ptl < np;
    const int ld = pok ? (p0 + ptl) : cs;
    const float4 pi = sp4[ld];
    const int orig = sidx[ld];

    // group-local init: this group's own LDS only (within-wave ordering)
    if (slice == 0) cnt_s[ptl] = 0;
    if (slice < 16) okey_s[ptl][slice] = ~0ULL;

    // phase 1: per-slice 2 smallest distances, capturing staged distances
    // in registers (fully unrolled -> stays in VGPRs, not scratch)
    float dv[NSTAGE];
    float t0 = 3.0e38f, t1 = 3.0e38f;  // t0 <= t1
    #pragma unroll
    for (int j = 0; j < NSTAGE; ++j) {
      int idx = slice + j * 32;
      float d = 3.0e38f;
      if (idx < tstage) d = dist2(pi, cpos[idx]);
      dv[j] = d;
      if (d < t1) {
        if (d < t0) { t1 = t0; t0 = d; } else { t1 = d; }
      }
    }
    for (int idx = slice + CAPC; idx < total; idx += 32) {   // overflow (~never)
      int c = 0;
      while (c + 1 < nc && pref_s[c + 1] <= idx) ++c;
      float d = dist2(pi, sp4[cell_s0_s[c] + (idx - pref_s[c])]);
      if (d < t1) {
        if (d < t0) { t1 = t0; t0 = d; } else { t1 = d; }
      }
    }
    tv_s[ptl][slice * 2]     = t0;
    tv_s[ptl][slice * 2 + 1] = t1;

    // 16th-smallest of the 64-value union via strict-rank (broadcast reads;
    // same-array in-wave ordering guarantees tv writes are visible)
    int r0 = 0, r1 = 0;
    #pragma unroll 8
    for (int j = 0; j < 64; ++j) {
      float wv = tv_s[ptl][j];
      r0 += (wv < t0) ? 1 : 0;
      r1 += (wv < t1) ? 1 : 0;
    }
    float cand = fmaxf(r0 <= 15 ? t0 : -3.0e38f, r1 <= 15 ? t1 : -3.0e38f);
    cand = fmaxf(cand, __shfl_xor(cand, 1, 64));
    cand = fmaxf(cand, __shfl_xor(cand, 2, 64));
    cand = fmaxf(cand, __shfl_xor(cand, 4, 64));
    cand = fmaxf(cand, __shfl_xor(cand, 8, 64));
    cand = fmaxf(cand, __shfl_xor(cand, 16, 64));
    const float d16 = cand;   // >= true d16; #(d<=d16) >= 16 when total>=16

    // conservative guard box from d16 (contains the true 16-NN ball)
    const float rg = sqrtf(fmaxf(d16, 0.f)) * 1.001f + 1e-4f;
    const int lx = (int)fminf(fmaxf(floorf((pi.x - rg) * GDIM), 0.f), (float)(GDIM - 1));
    const int ux = (int)fminf(fmaxf(floorf((pi.x + rg) * GDIM), 0.f), (float)(GDIM - 1));
    const int ly = (int)fminf(fmaxf(floorf((pi.y - rg) * GDIM), 0.f), (float)(GDIM - 1));
    const int uy = (int)fminf(fmaxf(floorf((pi.y + rg) * GDIM), 0.f), (float)(GDIM - 1));
    const int lz = (int)fminf(fmaxf(floorf((pi.z - rg) * GDIM), 0.f), (float)(GDIM - 1));
    const int uz = (int)fminf(fmaxf(floorf((pi.z + rg) * GDIM), 0.f), (float)(GDIM - 1));
    const bool trigger = (lx < ax0 || ux > ax1 || ly < ay0 || uy > ay1 || lz < az0 || uz > az1);

    // phase 2: register replay -- LDS touched only on hits
    if (pok) {
      #pragma unroll
      for (int j = 0; j < NSTAGE; ++j) {
        int idx = slice + j * 32;
        float d = dv[j];
        if (idx < tstage && d <= d16) {
          int pos = atomicAdd(&cnt_s[ptl], 1);
          if (pos < CAP_H) hk_s[ptl][pos] = make_key(d, cidx[idx]);
        }
      }
      for (int idx = slice + CAPC; idx < total; idx += 32) {   // overflow (~never)
        int c = 0;
        while (c + 1 < nc && pref_s[c + 1] <= idx) ++c;
        int g = cell_s0_s[c] + (idx - pref_s[c]);
        float d = dist2(pi, sp4[g]);
        if (d <= d16) {
          int pos = atomicAdd(&cnt_s[ptl], 1);
          if (pos < CAP_H) hk_s[ptl][pos] = make_key(d, sidx[g]);
        }
      }
      if (trigger) {
        for (int cz = lz; cz <= uz; ++cz)
          for (int cy = ly; cy <= uy; ++cy)
            for (int cx = lx; cx <= ux; ++cx) {
              if (cx >= ax0 && cx <= ax1 && cy >= ay0 && cy <= ay1 && cz >= az0 && cz <= az1)
                continue;
              int cc = (cz * GDIM + cy) * GDIM + cx;
              int s0 = cell_start[cc], e0 = cell_start[cc + 1];
              for (int k = s0 + slice; k < e0; k += 32) {
                float d = dist2(pi, sp4[k]);
                if (d <= d16) {
                  int pos = atomicAdd(&cnt_s[ptl], 1);
                  if (pos < CAP_H) hk_s[ptl][pos] = make_key(d, sidx[k]);
                }
              }
            }
      }
    }

    const int cntr = cnt_s[ptl];
    const bool overflow = cntr > CAP_H;   // needs 97+ candidates <= d16 (~never)
    const int cnt = overflow ? 0 : cntr;

    // exact rank-select of top-16 among collected keys (in-wave ordered
    // vs this group's hk writes above)
    if (pok) {
      for (int i = slice; i < cnt; i += 32) {
        unsigned long long key = hk_s[ptl][i];
        int rk = 0;
        for (int j = 0; j < cnt; ++j) rk += (hk_s[ptl][j] < key) ? 1 : 0;
        if (rk < 16) okey_s[ptl][rk] = key;
      }
    }

    if (!overflow) {
      if (pok && slice < 16) {
        unsigned long long key = okey_s[ptl][15 - slice];
        nbr[orig * NSAMP + slice] = (int)(key & 0xFFFFFFFFu);
      }
    } else if (pok && slice == 0) {
      // exact serial fallback (~never taken)
      unsigned long long akm[16];
      #pragma unroll
      for (int s = 0; s < 16; ++s) akm[s] = ~0ULL;
      for (int idx2 = 0; idx2 < total; ++idx2) {
        float4 q; int qi;
        if (idx2 < CAPC) { q = cpos[idx2]; qi = cidx[idx2]; }
        else {
          int c = 0;
          while (c + 1 < nc && pref_s[c + 1] <= idx2) ++c;
          int g = cell_s0_s[c] + (idx2 - pref_s[c]);
          q = sp4[g]; qi = sidx[g];
        }
        chain_insert(akm, make_key(dist2(pi, q), qi));
      }
      float r;
      if (akm[0] == ~0ULL) r = 1e9f;
      else {
        unsigned int ord = (unsigned int)(akm[0] >> 32);
        unsigned int di = (ord & 0x80000000u) ? (ord ^ 0x80000000u) : ~ord;
        float dd = __uint_as_float(di);
        r = sqrtf(fmaxf(dd, 0.f)) * 1.001f + 1e-4f;
      }
      int flx = (int)fminf(fmaxf(floorf((pi.x - r) * GDIM), 0.f), (float)(GDIM - 1));
      int fux = (int)fminf(fmaxf(floorf((pi.x + r) * GDIM), 0.f), (float)(GDIM - 1));
      int fly = (int)fminf(fmaxf(floorf((pi.y - r) * GDIM), 0.f), (float)(GDIM - 1));
      int fuy = (int)fminf(fmaxf(floorf((pi.y + r) * GDIM), 0.f), (float)(GDIM - 1));
      int flz = (int)fminf(fmaxf(floorf((pi.z - r) * GDIM), 0.f), (float)(GDIM - 1));
      int fuz = (int)fminf(fmaxf(floorf((pi.z + r) * GDIM), 0.f), (float)(GDIM - 1));
      for (int cz = flz; cz <= fuz; ++cz)
        for (int cy = fly; cy <= fuy; ++cy)
          for (int cx = flx; cx <= fux; ++cx) {
            if (cx >= ax0 && cx <= ax1 && cy >= ay0 && cy <= ay1 && cz >= az0 && cz <= az1)
              continue;
            int cc = (cz * GDIM + cy) * GDIM + cx;
            int s0 = cell_start[cc], e0 = cell_start[cc + 1];
            for (int k = s0; k < e0; ++k)
              chain_insert(akm, make_key(dist2(pi, sp4[k]), sidx[k]));
          }
      #pragma unroll
      for (int s = 0; s < 16; ++s) nbr[orig * NSAMP + s] = (int)(akm[s] & 0xFFFFFFFFu);
    }
  }
}

// ---------------------------------------------------------------- fused per-point transform: 2 points/block, all-wave MFMA
// xqkv is ORIGINAL-order. Positions read from p4 directly.
__global__ __launch_bounds__(256) void fused_pt(
    const float4* __restrict__ p4, const int* __restrict__ sidx,
    const __hip_bfloat16* __restrict__ xqkv, const int* __restrict__ nbr,
    const float* __restrict__ pw1, const float* __restrict__ pb1,
    const float* __restrict__ pbng, const float* __restrict__ pbnb,
    const float* __restrict__ pbnm, const float* __restrict__ pbnv,
    const float* __restrict__ pw2, const float* __restrict__ pb2,
    const float* __restrict__ sc1, const float* __restrict__ of1,
    const __hip_bfloat16* __restrict__ l1wp, const float* __restrict__ l1b,
    const float* __restrict__ bn2g, const float* __restrict__ bn2b,
    const float* __restrict__ bn2m, const float* __restrict__ bn2v,
    const __hip_bfloat16* __restrict__ l2wp, const float* __restrict__ l2b,
    float* __restrict__ out) {
  __shared__ __align__(16) __hip_bfloat16 a_s[2][NSAMP][264];
  __shared__ __align__(16) __hip_bfloat16 h1_s[2][NSAMP][40];
  __shared__ float w_s[2][NSAMP][33];
  __shared__ float q3_s[2][NSAMP][4];
  __shared__ int jo[2][NSAMP];
  __shared__ float psum[2][2][264];
  __shared__ int iorig[2];

  const int b0 = blockIdx.x * 2;
  const int tid = threadIdx.x;

  if (tid < 32) {
    int spt = tid >> 4, t = tid & 15;
    int b = b0 + spt;
    int i = sidx[b];
    if (t == 0) iorig[spt] = i;
    int j = nbr[i * NSAMP + t];
    jo[spt][t] = j;
    float4 pj = p4[j];
    float4 pc = p4[i];
    float rx = pj.x - pc.x;
    float ry = pj.y - pc.y;
    float rz = pj.z - pc.z;
    #pragma unroll
    for (int c3 = 0; c3 < 3; ++c3) {
      float t2 = rx * pw1[0 * 3 + c3] + ry * pw1[1 * 3 + c3] + rz * pw1[2 * 3 + c3] + pb1[c3];
      t2 = (t2 - pbnm[c3]) * rsqrtf(pbnv[c3] + EPSBN) * pbng[c3] + pbnb[c3];
      q3_s[spt][t][c3] = fmaxf(t2, 0.f);
    }
  }
  __syncthreads();

  const int pt = tid >> 7;
  const int t127 = tid & 127;
  const int g = t127 >> 5;
  const int cg = (t127 & 31) * 8;
  const int brow = iorig[pt];

  float xqv[8], s1v[8], o1v[8], w20v[8], w21v[8], w22v[8], pb2v[8];
  {
    bf16x8 xq8 = *(const bf16x8*)&xqkv[(size_t)brow * 768 + cg];
    #pragma unroll
    for (int u = 0; u < 8; ++u) {
      int c = cg + u;
      xqv[u] = b2f(xq8[u]);
      s1v[u] = sc1[c];
      o1v[u] = of1[c];
      w20v[u] = pw2[c];
      w21v[u] = pw2[256 + c];
      w22v[u] = pw2[512 + c];
      pb2v[u] = pb2[c];
    }
  }

  #pragma unroll
  for (int pass = 0; pass < 4; ++pass) {
    int t = g + pass * 4;
    int k = jo[pt][t];
    float q30 = q3_s[pt][t][0], q31 = q3_s[pt][t][1], q32 = q3_s[pt][t][2];
    bf16x8 xk8 = *(const bf16x8*)&xqkv[(size_t)k * 768 + 256 + cg];
    bf16x8 av;
    #pragma unroll
    for (int u = 0; u < 8; ++u) {
      float prv = q30 * w20v[u] + q31 * w21v[u] + q32 * w22v[u] + pb2v[u];
      float r = b2f(xk8[u]) - xqv[u] + prv;
      av[u] = f2b(fmaxf(r * s1v[u] + o1v[u], 0.f));
    }
    *(bf16x8*)&a_s[pt][t][cg] = av;
  }
  __syncthreads();

  const int w = tid >> 6;
  const int lane = tid & 63;
  const int mpt = w >> 1, hh = w & 1;
  const int nn = lane & 15, q = lane >> 4;
  {
    f32x4 acc = {0.f, 0.f, 0.f, 0.f};
    #pragma unroll
    for (int k0 = 0; k0 < 256; k0 += 32) {
      bf16x8 a = *(const bf16x8*)&a_s[mpt][nn][k0 + q * 8];
      bf16x8 bb = *(const bf16x8*)&l1wp[hh * 4096 + (k0 >> 3) * 128 + q * 128 + nn * 8];
      acc = __builtin_amdgcn_mfma_f32_16x16x32_bf16(a, bb, acc, 0, 0, 0);
    }
    int h = hh * 16 + nn;
    float s2 = bn2g[h] * rsqrtf(bn2v[h] + EPSBN);
    float o2 = bn2b[h] - bn2m[h] * s2;
    float l1bh = l1b[h];
    #pragma unroll
    for (int r = 0; r < 4; ++r)
      h1_s[mpt][q * 4 + r][h] = __float2bfloat16(fmaxf((acc[r] + l1bh) * s2 + o2, 0.f));
  }
  __syncthreads();

  {
    bf16x8 a = *(const bf16x8*)&h1_s[mpt][nn][q * 8];
    bf16x8 bb = *(const bf16x8*)&l2wp[hh * 512 + q * 128 + nn * 8];
    f32x4 z = {0.f, 0.f, 0.f, 0.f};
    f32x4 d = __builtin_amdgcn_mfma_f32_16x16x32_bf16(a, bb, z, 0, 0, 0);
    int h = hh * 16 + nn;
    float l2bh = l2b[h];
    #pragma unroll
    for (int r = 0; r < 4; ++r) w_s[mpt][q * 4 + r][h] = d[r] + l2bh;
  }
  __syncthreads();

  if (tid < 64) {
    int spt = tid >> 5, h = tid & 31;
    float m = -1e30f;
    #pragma unroll
    for (int t = 0; t < NSAMP; ++t) m = fmaxf(m, w_s[spt][t][h]);
    float e[NSAMP];
    float ssum = 0.f;
    #pragma unroll
    for (int t = 0; t < NSAMP; ++t) { e[t] = __expf(w_s[spt][t][h] - m); ssum += e[t]; }
    float inv = 1.f / ssum;
    #pragma unroll
    for (int t = 0; t < NSAMP; ++t) w_s[spt][t][h] = e[t] * inv;
  }
  __syncthreads();

  const int hb = cg & 31;
  float acc8[8];
  #pragma unroll
  for (int u = 0; u < 8; ++u) acc8[u] = 0.f;
  #pragma unroll
  for (int pass = 0; pass < 4; ++pass) {
    int t = g + pass * 4;
    int k = jo[pt][t];
    float q30 = q3_s[pt][t][0], q31 = q3_s[pt][t][1], q32 = q3_s[pt][t][2];
    bf16x8 xv8 = *(const bf16x8*)&xqkv[(size_t)k * 768 + 512 + cg];
    #pragma unroll
    for (int u = 0; u < 8; ++u) {
      float prv = q30 * w20v[u] + q31 * w21v[u] + q32 * w22v[u] + pb2v[u];
      acc8[u] += (b2f(xv8[u]) + prv) * w_s[pt][t][hb + u];
    }
  }
  #pragma unroll
  for (int u = 0; u < 8; ++u) acc8[u] += __shfl_xor(acc8[u], 32, 64);
  if ((lane >> 5) == 0) {
    #pragma unroll
    for (int u = 0; u < 8; ++u) psum[mpt][hh][cg + u] = acc8[u];
  }
  __syncthreads();
  {
    int opt = tid >> 7;
    int c0 = (tid & 127) * 2;
    float v0 = psum[opt][0][c0] + psum[opt][1][c0];
    float v1 = psum[opt][0][c0 + 1] + psum[opt][1][c0 + 1];
    int io = iorig[opt];
    *(float2*)&out[(size_t)io * OUT_C + c0] = make_float2(v0, v1);
  }
}

// ---------------------------------------------------------------- launch
extern "C" void kernel_launch(void* const* d_in, const int* in_sizes, int n_in,
                              void* d_out, int out_size, void* d_ws, size_t ws_size,
                              hipStream_t stream) {
  const float* p    = (const float*)d_in[0];
  const float* x    = (const float*)d_in[1];
  const float* wq   = (const float*)d_in[2];
  const float* bq   = (const float*)d_in[3];
  const float* wk   = (const float*)d_in[4];
  const float* bk   = (const float*)d_in[5];
  const float* wv   = (const float*)d_in[6];
  const float* bv   = (const float*)d_in[7];
  const float* pw1  = (const float*)d_in[8];
  const float* pb1  = (const float*)d_in[9];
  const float* pbng = (const float*)d_in[10];
  const float* pbnb = (const float*)d_in[11];
  const float* pbnm = (const float*)d_in[12];
  const float* pbnv = (const float*)d_in[13];
  const float* pw2  = (const float*)d_in[14];
  const float* pb2  = (const float*)d_in[15];
  const float* bn1g = (const float*)d_in[16];
  const float* bn1b = (const float*)d_in[17];
  const float* bn1m = (const float*)d_in[18];
  const float* bn1v = (const float*)d_in[19];
  const float* l1w  = (const float*)d_in[20];
  const float* l1b  = (const float*)d_in[21];
  const float* bn2g = (const float*)d_in[22];
  const float* bn2b = (const float*)d_in[23];
  const float* bn2m = (const float*)d_in[24];
  const float* bn2v = (const float*)d_in[25];
  const float* l2w  = (const float*)d_in[26];
  const float* l2b  = (const float*)d_in[27];
  float* out = (float*)d_out;

  char* ws = (char*)d_ws;
  float4* p4       = (float4*)(ws + 0x000000);
  float*  biasp    = (float*)(ws + 0x040000);
  int*    cursor   = (int*)(ws + 0x042800);
  int*    cell_st  = (int*)(ws + 0x043000);
  int*    pt_cell  = (int*)(ws + 0x044000);
  float4* sp4      = (float4*)(ws + 0x050000);
  int*    sidx     = (int*)(ws + 0x070000);
  __hip_bfloat16* l1wp = (__hip_bfloat16*)(ws + 0x080000);
  __hip_bfloat16* l2wp = (__hip_bfloat16*)(ws + 0x084000);
  float*  sc1      = (float*)(ws + 0x085000);
  float*  of1      = (float*)(ws + 0x085800);
  int*    rank     = (int*)(ws + 0x088000);
  int*    nbr      = (int*)(ws + 0x090000);
  __hip_bfloat16* Bp   = (__hip_bfloat16*)(ws + 0x110000);
  __hip_bfloat16* xb   = (__hip_bfloat16*)(ws + 0x170000);  // 4MB, ends at 0x570000
  __hip_bfloat16* xqkv = (__hip_bfloat16*)(ws + 0x570000);

  prep_kernel<<<dim3(1024), dim3(256), 0, stream>>>(
      p, x, wq, wk, wv, bq, bk, bv, l1w, l2w, bn1g, bn1b, bn1m, bn1v,
      p4, Bp, biasp, xb, l1wp, l2wp, sc1, of1, cursor, pt_cell);
  scatter_gemm<<<dim3(GEMM_BLKS2 + 16), dim3(512), 0, stream>>>(
      p4, pt_cell, cell_st, cursor, sp4, sidx, rank, xb, Bp, biasp, xqkv);
  knn_grid<<<dim3(NCELL * 2), dim3(256), 0, stream>>>(sp4, sidx, cell_st, nbr);
  fused_pt<<<dim3(N_PTS / 2), dim3(256), 0, stream>>>(
      p4, sidx, xqkv, nbr, pw1, pb1, pbng, pbnb, pbnm, pbnv, pw2, pb2,
      sc1, of1, l1wp, l1b, bn2g, bn2b, bn2m, bn2v, l2wp, l2b, out);
}